// Round 1
// baseline (1331.421 us; speedup 1.0000x reference)
//
#include <hip/hip_runtime.h>
#include <cstdint>
#include <cstddef>

#define T_SEQ 4096
#define BATCH 2
#define HIDDEN 1024
#define NHEAD 8
#define DKV 128
#define BT (BATCH * T_SEQ)   // 8192
#define NCH 64               // chunks per batch
#define CHUNK_L 64
#define QSCALE 0.08838834764831845f

// ---------------------------------------------------------------------------
// GEMM (NT): C[M,N] = A[M,K] * W[N,K]^T   (both row-major, K contiguous)
// 128x128 tile, BK=16, 256 threads, 8x8 per thread.
// ---------------------------------------------------------------------------
__global__ __launch_bounds__(256) void gemm_nt(const float* __restrict__ A,
                                               const float* __restrict__ W,
                                               float* __restrict__ C,
                                               int M, int N, int K)
{
    __shared__ float As[16][132];
    __shared__ float Ws[16][132];
    const int bm = blockIdx.y * 128;
    const int bn = blockIdx.x * 128;
    const int tid = threadIdx.x;
    const int lr = tid >> 2;          // 0..63 row for staging
    const int lk = (tid & 3) * 4;     // 0,4,8,12 k-offset
    const int tm = (tid >> 4) * 8;    // output rows tm..tm+7
    const int tn4 = (tid & 15) * 4;   // output cols tn4..+3 and 64+tn4..+3

    float acc[8][8] = {};

    for (int k0 = 0; k0 < K; k0 += 16) {
#pragma unroll
        for (int half = 0; half < 2; ++half) {
            int r = lr + half * 64;
            float4 av = *(const float4*)&A[(size_t)(bm + r) * K + k0 + lk];
            As[lk + 0][r] = av.x; As[lk + 1][r] = av.y;
            As[lk + 2][r] = av.z; As[lk + 3][r] = av.w;
            float4 wv = *(const float4*)&W[(size_t)(bn + r) * K + k0 + lk];
            Ws[lk + 0][r] = wv.x; Ws[lk + 1][r] = wv.y;
            Ws[lk + 2][r] = wv.z; Ws[lk + 3][r] = wv.w;
        }
        __syncthreads();
#pragma unroll
        for (int kk = 0; kk < 16; ++kk) {
            float a[8], b[8];
            *(float4*)&a[0] = *(const float4*)&As[kk][tm];
            *(float4*)&a[4] = *(const float4*)&As[kk][tm + 4];
            *(float4*)&b[0] = *(const float4*)&Ws[kk][tn4];
            *(float4*)&b[4] = *(const float4*)&Ws[kk][64 + tn4];
#pragma unroll
            for (int i = 0; i < 8; ++i)
#pragma unroll
                for (int j = 0; j < 8; ++j)
                    acc[i][j] = fmaf(a[i], b[j], acc[i][j]);
        }
        __syncthreads();
    }
#pragma unroll
    for (int i = 0; i < 8; ++i) {
        float4 o0, o1;
        o0.x = acc[i][0]; o0.y = acc[i][1]; o0.z = acc[i][2]; o0.w = acc[i][3];
        o1.x = acc[i][4]; o1.y = acc[i][5]; o1.z = acc[i][6]; o1.w = acc[i][7];
        size_t row = (size_t)(bm + tm + i) * N + bn;
        *(float4*)&C[row + tn4] = o0;
        *(float4*)&C[row + 64 + tn4] = o1;
    }
}

// ---------------------------------------------------------------------------
// Causal depthwise conv (K=4) + SiLU.  X,Y: [BT, HIDDEN], Wc: [HIDDEN,4]
// out[t] = silu(sum_i x[t-3+i] * w[:,i]) with zero pad at batch start.
// ---------------------------------------------------------------------------
__global__ void conv_silu(const float* __restrict__ X,
                          const float* __restrict__ Wc,
                          float* __restrict__ Y)
{
    int idx = blockIdx.x * 256 + threadIdx.x;      // BT*HIDDEN total
    int d = idx & (HIDDEN - 1);
    int r = idx >> 10;
    int t = r & (T_SEQ - 1);
    float4 w = *(const float4*)&Wc[d * 4];
    float acc = X[idx] * w.w;
    if (t >= 1) acc = fmaf(X[idx - HIDDEN], w.z, acc);
    if (t >= 2) acc = fmaf(X[idx - 2 * HIDDEN], w.y, acc);
    if (t >= 3) acc = fmaf(X[idx - 3 * HIDDEN], w.x, acc);
    Y[idx] = acc / (1.f + __expf(-acc));
}

// ---------------------------------------------------------------------------
// Hadamard feature map per head: OUT[r, h*128+e] =
//   (sum_d X[r,h*128+d]*W1[e,d] + B1[e]) * (sum_d X*W2 + B2[e])
// block = (64 rows, 1 head); 256 threads; K slabs of 16.
// ---------------------------------------------------------------------------
__global__ __launch_bounds__(256) void fm_kernel(const float* __restrict__ X,
                                                 const float* __restrict__ W1,
                                                 const float* __restrict__ B1,
                                                 const float* __restrict__ W2,
                                                 const float* __restrict__ B2,
                                                 float* __restrict__ OUT)
{
    __shared__ float xs[64][132];
    __shared__ float w1s[16][132];
    __shared__ float w2s[16][132];
    const int h = blockIdx.y;
    const int r0 = blockIdx.x * 64;
    const int tid = threadIdx.x;

#pragma unroll
    for (int i = 0; i < 8; ++i) {
        int p = tid + 256 * i;              // float4 index, 2048 total
        int row = p >> 5, c4 = (p & 31) * 4;
        float4 v = *(const float4*)&X[(size_t)(r0 + row) * HIDDEN + h * DKV + c4];
        *(float4*)&xs[row][c4] = v;
    }

    const int tr = tid >> 4;          // rows tr + 16*rr
    const int te4 = (tid & 15) * 4;   // cols te4..+3, 64+te4..+3
    float acc1[4][8] = {}, acc2[4][8] = {};

    for (int ks0 = 0; ks0 < 128; ks0 += 16) {
        __syncthreads();
#pragma unroll
        for (int i = 0; i < 2; ++i) {
            int q = tid + 256 * i;           // 512 float4 per matrix slab
            int e = q >> 2, d4 = (q & 3) * 4;
            float4 a = *(const float4*)&W1[(size_t)e * DKV + ks0 + d4];
            w1s[d4 + 0][e] = a.x; w1s[d4 + 1][e] = a.y;
            w1s[d4 + 2][e] = a.z; w1s[d4 + 3][e] = a.w;
            float4 b = *(const float4*)&W2[(size_t)e * DKV + ks0 + d4];
            w2s[d4 + 0][e] = b.x; w2s[d4 + 1][e] = b.y;
            w2s[d4 + 2][e] = b.z; w2s[d4 + 3][e] = b.w;
        }
        __syncthreads();
#pragma unroll
        for (int dd = 0; dd < 16; ++dd) {
            float xv[4];
#pragma unroll
            for (int rr = 0; rr < 4; ++rr) xv[rr] = xs[tr + 16 * rr][ks0 + dd];
            float wa[8], wb[8];
            *(float4*)&wa[0] = *(const float4*)&w1s[dd][te4];
            *(float4*)&wa[4] = *(const float4*)&w1s[dd][64 + te4];
            *(float4*)&wb[0] = *(const float4*)&w2s[dd][te4];
            *(float4*)&wb[4] = *(const float4*)&w2s[dd][64 + te4];
#pragma unroll
            for (int rr = 0; rr < 4; ++rr)
#pragma unroll
                for (int j = 0; j < 8; ++j) {
                    acc1[rr][j] = fmaf(xv[rr], wa[j], acc1[rr][j]);
                    acc2[rr][j] = fmaf(xv[rr], wb[j], acc2[rr][j]);
                }
        }
    }

    float b1v[8], b2v[8];
    *(float4*)&b1v[0] = *(const float4*)&B1[te4];
    *(float4*)&b1v[4] = *(const float4*)&B1[64 + te4];
    *(float4*)&b2v[0] = *(const float4*)&B2[te4];
    *(float4*)&b2v[4] = *(const float4*)&B2[64 + te4];
#pragma unroll
    for (int rr = 0; rr < 4; ++rr) {
        int row = r0 + tr + 16 * rr;
        float o[8];
#pragma unroll
        for (int j = 0; j < 8; ++j)
            o[j] = (acc1[rr][j] + b1v[j]) * (acc2[rr][j] + b2v[j]);
        size_t base = (size_t)row * HIDDEN + h * DKV;
        *(float4*)&OUT[base + te4] = *(float4*)&o[0];
        *(float4*)&OUT[base + 64 + te4] = *(float4*)&o[4];
    }
}

// ---------------------------------------------------------------------------
// Per-chunk K^T V: G[bh][c][dk][dv] = sum_{j<64} Kf[row j][dk] * V[row j][dv]
// block = (chunk c, bh); 256 threads, 8x8 per thread.
// ---------------------------------------------------------------------------
__global__ __launch_bounds__(256) void ktv_kernel(const float* __restrict__ Kf,
                                                  const float* __restrict__ V,
                                                  float* __restrict__ G)
{
    __shared__ float ks[64][128];
    __shared__ float vs[64][128];
    const int c = blockIdx.x;
    const int bh = blockIdx.y;
    const int b = bh >> 3, h = bh & 7;
    const int tid = threadIdx.x;
    const size_t rowbase = (size_t)b * T_SEQ + (size_t)c * CHUNK_L;

#pragma unroll
    for (int i = 0; i < 8; ++i) {
        int p = tid + 256 * i;
        int row = p >> 5, c4 = (p & 31) * 4;
        size_t g = (rowbase + row) * HIDDEN + h * DKV + c4;
        *(float4*)&ks[row][c4] = *(const float4*)&Kf[g];
        *(float4*)&vs[row][c4] = *(const float4*)&V[g];
    }
    __syncthreads();

    const int tk = (tid >> 4) * 8;
    const int tv4 = (tid & 15) * 4;
    float acc[8][8] = {};
    for (int j = 0; j < 64; ++j) {
        float kv[8], vv[8];
        *(float4*)&kv[0] = *(const float4*)&ks[j][tk];
        *(float4*)&kv[4] = *(const float4*)&ks[j][tk + 4];
        *(float4*)&vv[0] = *(const float4*)&vs[j][tv4];
        *(float4*)&vv[4] = *(const float4*)&vs[j][64 + tv4];
#pragma unroll
        for (int a = 0; a < 8; ++a)
#pragma unroll
            for (int q = 0; q < 8; ++q)
                acc[a][q] = fmaf(kv[a], vv[q], acc[a][q]);
    }
    float* Gp = G + ((size_t)bh * NCH + c) * (DKV * DKV);
#pragma unroll
    for (int a = 0; a < 8; ++a) {
        size_t ro = (size_t)(tk + a) * DKV;
        *(float4*)&Gp[ro + tv4] = *(float4*)&acc[a][0];
        *(float4*)&Gp[ro + 64 + tv4] = *(float4*)&acc[a][4];
    }
}

// ---------------------------------------------------------------------------
// Exclusive prefix over chunk dim, in place. One thread per (bh, dk, dv).
// ---------------------------------------------------------------------------
__global__ void prefix_kernel(float* __restrict__ G)
{
    int idx = blockIdx.x * 256 + threadIdx.x;   // 16 * 16384
    int bh = idx >> 14;
    int e = idx & 16383;
    float* p = G + (size_t)bh * NCH * 16384 + e;
    float run = 0.f;
#pragma unroll
    for (int c = 0; c < NCH; ++c) {
        float t = p[(size_t)c * 16384];
        p[(size_t)c * 16384] = run;
        run += t;
    }
}

// ---------------------------------------------------------------------------
// Per-chunk output: O = tril(q k^T) v + q S     (q pre-scaled)
// block = (chunk c, bh); 256 threads. j streamed in tiles of 16 to fit 64KB LDS.
// ---------------------------------------------------------------------------
__global__ __launch_bounds__(256) void attn_kernel(const float* __restrict__ Qf,
                                                   const float* __restrict__ Kf,
                                                   const float* __restrict__ V,
                                                   const float* __restrict__ S,
                                                   float* __restrict__ O)
{
    __shared__ float qs[64][132];
    __shared__ float kt[16][132];
    __shared__ float vt[16][132];
    __shared__ float at[64][20];
    __shared__ float ss[16][132];
    const int c = blockIdx.x;
    const int bh = blockIdx.y;
    const int b = bh >> 3, h = bh & 7;
    const int tid = threadIdx.x;
    const size_t rowbase = (size_t)b * T_SEQ + (size_t)c * CHUNK_L;

#pragma unroll
    for (int i = 0; i < 8; ++i) {
        int p = tid + 256 * i;
        int row = p >> 5, c4 = (p & 31) * 4;
        float4 v = *(const float4*)&Qf[(rowbase + row) * HIDDEN + h * DKV + c4];
        v.x *= QSCALE; v.y *= QSCALE; v.z *= QSCALE; v.w *= QSCALE;
        *(float4*)&qs[row][c4] = v;
    }

    const int ti1 = (tid >> 2) & 15;    // score rows ti1 + 16*ii
    const int tj = (tid & 3) * 4;       // score cols tj..tj+3 (within tile)
    const int ti2 = tid >> 4;           // out rows ti2 + 16*ii
    const int tv4 = (tid & 15) * 4;     // out cols tv4..+3, 64+tv4..+3
    float oacc[4][8] = {};

    for (int jt = 0; jt < 4; ++jt) {
        __syncthreads();
#pragma unroll
        for (int i = 0; i < 2; ++i) {
            int q = tid + 256 * i;           // 512 float4 (16 rows x 32)
            int row = q >> 5, c4 = (q & 31) * 4;
            size_t g = (rowbase + jt * 16 + row) * HIDDEN + h * DKV + c4;
            *(float4*)&kt[row][c4] = *(const float4*)&Kf[g];
            *(float4*)&vt[row][c4] = *(const float4*)&V[g];
        }
        __syncthreads();

        float sc[4][4] = {};
        for (int d = 0; d < 128; d += 4) {
            float4 kv[4];
#pragma unroll
            for (int jj = 0; jj < 4; ++jj)
                kv[jj] = *(const float4*)&kt[tj + jj][d];
#pragma unroll
            for (int ii = 0; ii < 4; ++ii) {
                float4 qv = *(const float4*)&qs[ti1 + 16 * ii][d];
#pragma unroll
                for (int jj = 0; jj < 4; ++jj)
                    sc[ii][jj] += qv.x * kv[jj].x + qv.y * kv[jj].y +
                                  qv.z * kv[jj].z + qv.w * kv[jj].w;
            }
        }
#pragma unroll
        for (int ii = 0; ii < 4; ++ii) {
            int i = ti1 + 16 * ii;
#pragma unroll
            for (int jj = 0; jj < 4; ++jj) {
                int j = jt * 16 + tj + jj;
                at[i][tj + jj] = (j <= i) ? sc[ii][jj] : 0.f;
            }
        }
        __syncthreads();

#pragma unroll
        for (int j = 0; j < 16; ++j) {
            float av[4];
#pragma unroll
            for (int ii = 0; ii < 4; ++ii) av[ii] = at[ti2 + 16 * ii][j];
            float vv[8];
            *(float4*)&vv[0] = *(const float4*)&vt[j][tv4];
            *(float4*)&vv[4] = *(const float4*)&vt[j][64 + tv4];
#pragma unroll
            for (int ii = 0; ii < 4; ++ii)
#pragma unroll
                for (int jj = 0; jj < 8; ++jj)
                    oacc[ii][jj] = fmaf(av[ii], vv[jj], oacc[ii][jj]);
        }
    }

    // inter-chunk: oacc += q @ S, S streamed in 16-row slabs
    const float* Sp = S + ((size_t)bh * NCH + c) * (DKV * DKV);
    for (int d0 = 0; d0 < 128; d0 += 16) {
        __syncthreads();
#pragma unroll
        for (int i = 0; i < 2; ++i) {
            int q = tid + 256 * i;
            int row = q >> 5, c4 = (q & 31) * 4;
            *(float4*)&ss[row][c4] = *(const float4*)&Sp[(size_t)(d0 + row) * DKV + c4];
        }
        __syncthreads();
#pragma unroll
        for (int kk = 0; kk < 16; ++kk) {
            float qv[4];
#pragma unroll
            for (int ii = 0; ii < 4; ++ii) qv[ii] = qs[ti2 + 16 * ii][d0 + kk];
            float sv[8];
            *(float4*)&sv[0] = *(const float4*)&ss[kk][tv4];
            *(float4*)&sv[4] = *(const float4*)&ss[kk][64 + tv4];
#pragma unroll
            for (int ii = 0; ii < 4; ++ii)
#pragma unroll
                for (int jj = 0; jj < 8; ++jj)
                    oacc[ii][jj] = fmaf(qv[ii], sv[jj], oacc[ii][jj]);
        }
    }

#pragma unroll
    for (int ii = 0; ii < 4; ++ii) {
        size_t base = (rowbase + ti2 + 16 * ii) * HIDDEN + h * DKV;
        *(float4*)&O[base + tv4] = *(float4*)&oacc[ii][0];
        *(float4*)&O[base + 64 + tv4] = *(float4*)&oacc[ii][4];
    }
}

// ---------------------------------------------------------------------------
extern "C" void kernel_launch(void* const* d_in, const int* in_sizes, int n_in,
                              void* d_out, int out_size, void* d_ws, size_t ws_size,
                              hipStream_t stream)
{
    (void)in_sizes; (void)n_in; (void)out_size; (void)ws_size;
    const float* hs = (const float*)d_in[0];
    const float* wq = (const float*)d_in[1];
    const float* wk = (const float*)d_in[2];
    const float* wv = (const float*)d_in[3];
    const float* wo = (const float*)d_in[4];
    const float* cq = (const float*)d_in[5];
    const float* ck = (const float*)d_in[6];
    const float* cv = (const float*)d_in[7];
    const float* fmq_w1 = (const float*)d_in[8];
    const float* fmq_b1 = (const float*)d_in[9];
    const float* fmq_w2 = (const float*)d_in[10];
    const float* fmq_b2 = (const float*)d_in[11];
    const float* fmk_w1 = (const float*)d_in[12];
    const float* fmk_b1 = (const float*)d_in[13];
    const float* fmk_w2 = (const float*)d_in[14];
    const float* fmk_b2 = (const float*)d_in[15];
    float* out = (float*)d_out;
    float* ws = (float*)d_ws;

    const size_t SZ = (size_t)BT * HIDDEN;   // 8,388,608 floats = 32 MiB
    float* R0 = ws;            // qlin -> qf
    float* R1 = ws + SZ;       // klin -> kf
    float* R2 = ws + 2 * SZ;   // vlin -> o (attention out)
    float* R3 = ws + 3 * SZ;   // v (conv+silu)
    float* R4 = ws + 4 * SZ;   // qc, later G (spans R4..R5)
    float* R5 = ws + 5 * SZ;   // kc
    float* G = R4;             // [16][64][128][128] fp32, 64 MiB

    dim3 gg(HIDDEN / 128, BT / 128);         // (8, 64)
    gemm_nt<<<gg, 256, 0, stream>>>(hs, wq, R0, BT, HIDDEN, HIDDEN);
    gemm_nt<<<gg, 256, 0, stream>>>(hs, wk, R1, BT, HIDDEN, HIDDEN);
    gemm_nt<<<gg, 256, 0, stream>>>(hs, wv, R2, BT, HIDDEN, HIDDEN);

    int tot = BT * HIDDEN;
    conv_silu<<<tot / 256, 256, 0, stream>>>(R0, cq, R4);
    conv_silu<<<tot / 256, 256, 0, stream>>>(R1, ck, R5);
    conv_silu<<<tot / 256, 256, 0, stream>>>(R2, cv, R3);

    dim3 fg(BT / 64, NHEAD);                 // (128, 8)
    fm_kernel<<<fg, 256, 0, stream>>>(R4, fmq_w1, fmq_b1, fmq_w2, fmq_b2, R0);
    fm_kernel<<<fg, 256, 0, stream>>>(R5, fmk_w1, fmk_b1, fmk_w2, fmk_b2, R1);

    dim3 ag(NCH, BATCH * NHEAD);             // (64, 16)
    ktv_kernel<<<ag, 256, 0, stream>>>(R1, R3, G);
    prefix_kernel<<<(16 * 16384) / 256, 256, 0, stream>>>(G);
    attn_kernel<<<ag, 256, 0, stream>>>(R0, R1, R3, G, R2);

    gemm_nt<<<gg, 256, 0, stream>>>(R2, wo, out, BT, HIDDEN, HIDDEN);
}

// Round 2
// 639.719 us; speedup vs baseline: 2.0813x; 2.0813x over previous
//
#include <hip/hip_runtime.h>
#include <cstdint>
#include <cstddef>

#define T_SEQ 4096
#define BATCH 2
#define HIDDEN 1024
#define NHEAD 8
#define DKV 128
#define BT (BATCH * T_SEQ)   // 8192
#define NCH 64               // chunks per batch
#define CHUNK_L 64
#define QSCALE 0.08838834764831845f

typedef _Float16 half8 __attribute__((ext_vector_type(8)));
typedef float floatx4 __attribute__((ext_vector_type(4)));

// ---------------------------------------------------------------------------
// fp32 -> fp16 cast, 8 elements/thread
// ---------------------------------------------------------------------------
__global__ void cast_f32_f16(const float* __restrict__ X, _Float16* __restrict__ Y, int n8)
{
    int idx = blockIdx.x * 256 + threadIdx.x;
    if (idx < n8) {
        float4 a = ((const float4*)X)[idx * 2];
        float4 b = ((const float4*)X)[idx * 2 + 1];
        half8 h = { (_Float16)a.x, (_Float16)a.y, (_Float16)a.z, (_Float16)a.w,
                    (_Float16)b.x, (_Float16)b.y, (_Float16)b.z, (_Float16)b.w };
        *(half8*)&Y[idx * 8] = h;
    }
}

// ---------------------------------------------------------------------------
// GEMM (NT) fp16 MFMA: C[M,N] fp32 = A16[M,K] * W16[N,K]^T  (K contiguous)
// 128x128 tile, BK=32, 256 threads = 4 waves (2x2), 64x64 per wave.
// Staging via global_load_lds width=16. LDS tiles [128][32] halfs, unpadded
// (b128 frag reads spread uniformly: 8 accesses/bank = optimal).
// ---------------------------------------------------------------------------
__global__ __launch_bounds__(256) void gemm_nt_f16(const _Float16* __restrict__ A,
                                                   const _Float16* __restrict__ W,
                                                   float* __restrict__ C,
                                                   int M, int N, int K)
{
    __shared__ _Float16 As[128 * 32];
    __shared__ _Float16 Ws[128 * 32];
    const int bm = blockIdx.y * 128;
    const int bn = blockIdx.x * 128;
    const int tid = threadIdx.x;
    const int w = tid >> 6;          // wave 0..3
    const int l = tid & 63;
    const int wm = (w >> 1) * 64;    // wave row offset in tile
    const int wn = (w & 1) * 64;     // wave col offset in tile
    const int lane16 = l & 15;
    const int quad = l >> 4;

    // staging: linear16 = c*256 + w*64 + l; row = linear16>>2; kh = (l&3)*8
    const int srow = w * 16 + (l >> 2);
    const int skh = (l & 3) * 8;

    floatx4 acc[4][4];
#pragma unroll
    for (int i = 0; i < 4; ++i)
#pragma unroll
        for (int j = 0; j < 4; ++j)
            acc[i][j] = (floatx4){0.f, 0.f, 0.f, 0.f};

    for (int k0 = 0; k0 < K; k0 += 32) {
#pragma unroll
        for (int c = 0; c < 2; ++c) {
            int row = c * 64 + srow;
            const _Float16* ga = A + (size_t)(bm + row) * K + k0 + skh;
            const _Float16* gw = W + (size_t)(bn + row) * K + k0 + skh;
            __builtin_amdgcn_global_load_lds(
                (const __attribute__((address_space(1))) void*)ga,
                (__attribute__((address_space(3))) void*)(As + c * 2048 + w * 512),
                16, 0, 0);
            __builtin_amdgcn_global_load_lds(
                (const __attribute__((address_space(1))) void*)gw,
                (__attribute__((address_space(3))) void*)(Ws + c * 2048 + w * 512),
                16, 0, 0);
        }
        __syncthreads();

        half8 a[4], b[4];
#pragma unroll
        for (int i = 0; i < 4; ++i) {
            a[i] = *(const half8*)&As[(wm + i * 16 + lane16) * 32 + quad * 8];
            b[i] = *(const half8*)&Ws[(wn + i * 16 + lane16) * 32 + quad * 8];
        }
#pragma unroll
        for (int i = 0; i < 4; ++i)
#pragma unroll
            for (int j = 0; j < 4; ++j)
                acc[i][j] = __builtin_amdgcn_mfma_f32_16x16x32_f16(a[i], b[j], acc[i][j], 0, 0, 0);
        __syncthreads();
    }

    // C/D layout: col = lane&15, row = (lane>>4)*4 + reg   [measured m89/m91]
#pragma unroll
    for (int i = 0; i < 4; ++i)
#pragma unroll
        for (int j = 0; j < 4; ++j)
#pragma unroll
            for (int r = 0; r < 4; ++r)
                C[(size_t)(bm + wm + i * 16 + quad * 4 + r) * N + bn + wn + j * 16 + lane16] =
                    acc[i][j][r];
}

// ---------------------------------------------------------------------------
// Causal depthwise conv (K=4) + SiLU.  X,Y: [BT, HIDDEN], Wc: [HIDDEN,4]
// ---------------------------------------------------------------------------
__global__ void conv_silu(const float* __restrict__ X,
                          const float* __restrict__ Wc,
                          float* __restrict__ Y)
{
    int idx = blockIdx.x * 256 + threadIdx.x;      // BT*HIDDEN total
    int d = idx & (HIDDEN - 1);
    int r = idx >> 10;
    int t = r & (T_SEQ - 1);
    float4 w = *(const float4*)&Wc[d * 4];
    float acc = X[idx] * w.w;
    if (t >= 1) acc = fmaf(X[idx - HIDDEN], w.z, acc);
    if (t >= 2) acc = fmaf(X[idx - 2 * HIDDEN], w.y, acc);
    if (t >= 3) acc = fmaf(X[idx - 3 * HIDDEN], w.x, acc);
    Y[idx] = acc / (1.f + __expf(-acc));
}

// ---------------------------------------------------------------------------
// Hadamard feature map per head (fp32 SIMT)
// ---------------------------------------------------------------------------
__global__ __launch_bounds__(256) void fm_kernel(const float* __restrict__ X,
                                                 const float* __restrict__ W1,
                                                 const float* __restrict__ B1,
                                                 const float* __restrict__ W2,
                                                 const float* __restrict__ B2,
                                                 float* __restrict__ OUT)
{
    __shared__ float xs[64][132];
    __shared__ float w1s[16][132];
    __shared__ float w2s[16][132];
    const int h = blockIdx.y;
    const int r0 = blockIdx.x * 64;
    const int tid = threadIdx.x;

#pragma unroll
    for (int i = 0; i < 8; ++i) {
        int p = tid + 256 * i;              // float4 index, 2048 total
        int row = p >> 5, c4 = (p & 31) * 4;
        float4 v = *(const float4*)&X[(size_t)(r0 + row) * HIDDEN + h * DKV + c4];
        *(float4*)&xs[row][c4] = v;
    }

    const int tr = tid >> 4;          // rows tr + 16*rr
    const int te4 = (tid & 15) * 4;   // cols te4..+3, 64+te4..+3
    float acc1[4][8] = {}, acc2[4][8] = {};

    for (int ks0 = 0; ks0 < 128; ks0 += 16) {
        __syncthreads();
#pragma unroll
        for (int i = 0; i < 2; ++i) {
            int q = tid + 256 * i;           // 512 float4 per matrix slab
            int e = q >> 2, d4 = (q & 3) * 4;
            float4 a = *(const float4*)&W1[(size_t)e * DKV + ks0 + d4];
            w1s[d4 + 0][e] = a.x; w1s[d4 + 1][e] = a.y;
            w1s[d4 + 2][e] = a.z; w1s[d4 + 3][e] = a.w;
            float4 b = *(const float4*)&W2[(size_t)e * DKV + ks0 + d4];
            w2s[d4 + 0][e] = b.x; w2s[d4 + 1][e] = b.y;
            w2s[d4 + 2][e] = b.z; w2s[d4 + 3][e] = b.w;
        }
        __syncthreads();
#pragma unroll
        for (int dd = 0; dd < 16; ++dd) {
            float xv[4];
#pragma unroll
            for (int rr = 0; rr < 4; ++rr) xv[rr] = xs[tr + 16 * rr][ks0 + dd];
            float wa[8], wb[8];
            *(float4*)&wa[0] = *(const float4*)&w1s[dd][te4];
            *(float4*)&wa[4] = *(const float4*)&w1s[dd][64 + te4];
            *(float4*)&wb[0] = *(const float4*)&w2s[dd][te4];
            *(float4*)&wb[4] = *(const float4*)&w2s[dd][64 + te4];
#pragma unroll
            for (int rr = 0; rr < 4; ++rr)
#pragma unroll
                for (int j = 0; j < 8; ++j) {
                    acc1[rr][j] = fmaf(xv[rr], wa[j], acc1[rr][j]);
                    acc2[rr][j] = fmaf(xv[rr], wb[j], acc2[rr][j]);
                }
        }
    }

    float b1v[8], b2v[8];
    *(float4*)&b1v[0] = *(const float4*)&B1[te4];
    *(float4*)&b1v[4] = *(const float4*)&B1[64 + te4];
    *(float4*)&b2v[0] = *(const float4*)&B2[te4];
    *(float4*)&b2v[4] = *(const float4*)&B2[64 + te4];
#pragma unroll
    for (int rr = 0; rr < 4; ++rr) {
        int row = r0 + tr + 16 * rr;
        float o[8];
#pragma unroll
        for (int j = 0; j < 8; ++j)
            o[j] = (acc1[rr][j] + b1v[j]) * (acc2[rr][j] + b2v[j]);
        size_t base = (size_t)row * HIDDEN + h * DKV;
        *(float4*)&OUT[base + te4] = *(float4*)&o[0];
        *(float4*)&OUT[base + 64 + te4] = *(float4*)&o[4];
    }
}

// ---------------------------------------------------------------------------
// Per-chunk K^T V
// ---------------------------------------------------------------------------
__global__ __launch_bounds__(256) void ktv_kernel(const float* __restrict__ Kf,
                                                  const float* __restrict__ V,
                                                  float* __restrict__ G)
{
    __shared__ float ks[64][128];
    __shared__ float vs[64][128];
    const int c = blockIdx.x;
    const int bh = blockIdx.y;
    const int b = bh >> 3, h = bh & 7;
    const int tid = threadIdx.x;
    const size_t rowbase = (size_t)b * T_SEQ + (size_t)c * CHUNK_L;

#pragma unroll
    for (int i = 0; i < 8; ++i) {
        int p = tid + 256 * i;
        int row = p >> 5, c4 = (p & 31) * 4;
        size_t g = (rowbase + row) * HIDDEN + h * DKV + c4;
        *(float4*)&ks[row][c4] = *(const float4*)&Kf[g];
        *(float4*)&vs[row][c4] = *(const float4*)&V[g];
    }
    __syncthreads();

    const int tk = (tid >> 4) * 8;
    const int tv4 = (tid & 15) * 4;
    float acc[8][8] = {};
    for (int j = 0; j < 64; ++j) {
        float kv[8], vv[8];
        *(float4*)&kv[0] = *(const float4*)&ks[j][tk];
        *(float4*)&kv[4] = *(const float4*)&ks[j][tk + 4];
        *(float4*)&vv[0] = *(const float4*)&vs[j][tv4];
        *(float4*)&vv[4] = *(const float4*)&vs[j][64 + tv4];
#pragma unroll
        for (int a = 0; a < 8; ++a)
#pragma unroll
            for (int q = 0; q < 8; ++q)
                acc[a][q] = fmaf(kv[a], vv[q], acc[a][q]);
    }
    float* Gp = G + ((size_t)bh * NCH + c) * (DKV * DKV);
#pragma unroll
    for (int a = 0; a < 8; ++a) {
        size_t ro = (size_t)(tk + a) * DKV;
        *(float4*)&Gp[ro + tv4] = *(float4*)&acc[a][0];
        *(float4*)&Gp[ro + 64 + tv4] = *(float4*)&acc[a][4];
    }
}

// ---------------------------------------------------------------------------
// Exclusive prefix over chunk dim, in place.
// ---------------------------------------------------------------------------
__global__ void prefix_kernel(float* __restrict__ G)
{
    int idx = blockIdx.x * 256 + threadIdx.x;   // 16 * 16384
    int bh = idx >> 14;
    int e = idx & 16383;
    float* p = G + (size_t)bh * NCH * 16384 + e;
    float run = 0.f;
#pragma unroll
    for (int c = 0; c < NCH; ++c) {
        float t = p[(size_t)c * 16384];
        p[(size_t)c * 16384] = run;
        run += t;
    }
}

// ---------------------------------------------------------------------------
// Per-chunk output: O = tril(q k^T) v + q S     (q pre-scaled)
// ---------------------------------------------------------------------------
__global__ __launch_bounds__(256) void attn_kernel(const float* __restrict__ Qf,
                                                   const float* __restrict__ Kf,
                                                   const float* __restrict__ V,
                                                   const float* __restrict__ S,
                                                   float* __restrict__ O)
{
    __shared__ float qs[64][132];
    __shared__ float kt[16][132];
    __shared__ float vt[16][132];
    __shared__ float at[64][20];
    __shared__ float ss[16][132];
    const int c = blockIdx.x;
    const int bh = blockIdx.y;
    const int b = bh >> 3, h = bh & 7;
    const int tid = threadIdx.x;
    const size_t rowbase = (size_t)b * T_SEQ + (size_t)c * CHUNK_L;

#pragma unroll
    for (int i = 0; i < 8; ++i) {
        int p = tid + 256 * i;
        int row = p >> 5, c4 = (p & 31) * 4;
        float4 v = *(const float4*)&Qf[(rowbase + row) * HIDDEN + h * DKV + c4];
        v.x *= QSCALE; v.y *= QSCALE; v.z *= QSCALE; v.w *= QSCALE;
        *(float4*)&qs[row][c4] = v;
    }

    const int ti1 = (tid >> 2) & 15;
    const int tj = (tid & 3) * 4;
    const int ti2 = tid >> 4;
    const int tv4 = (tid & 15) * 4;
    float oacc[4][8] = {};

    for (int jt = 0; jt < 4; ++jt) {
        __syncthreads();
#pragma unroll
        for (int i = 0; i < 2; ++i) {
            int q = tid + 256 * i;
            int row = q >> 5, c4 = (q & 31) * 4;
            size_t g = (rowbase + jt * 16 + row) * HIDDEN + h * DKV + c4;
            *(float4*)&kt[row][c4] = *(const float4*)&Kf[g];
            *(float4*)&vt[row][c4] = *(const float4*)&V[g];
        }
        __syncthreads();

        float sc[4][4] = {};
        for (int d = 0; d < 128; d += 4) {
            float4 kv[4];
#pragma unroll
            for (int jj = 0; jj < 4; ++jj)
                kv[jj] = *(const float4*)&kt[tj + jj][d];
#pragma unroll
            for (int ii = 0; ii < 4; ++ii) {
                float4 qv = *(const float4*)&qs[ti1 + 16 * ii][d];
#pragma unroll
                for (int jj = 0; jj < 4; ++jj)
                    sc[ii][jj] += qv.x * kv[jj].x + qv.y * kv[jj].y +
                                  qv.z * kv[jj].z + qv.w * kv[jj].w;
            }
        }
#pragma unroll
        for (int ii = 0; ii < 4; ++ii) {
            int i = ti1 + 16 * ii;
#pragma unroll
            for (int jj = 0; jj < 4; ++jj) {
                int j = jt * 16 + tj + jj;
                at[i][tj + jj] = (j <= i) ? sc[ii][jj] : 0.f;
            }
        }
        __syncthreads();

#pragma unroll
        for (int j = 0; j < 16; ++j) {
            float av[4];
#pragma unroll
            for (int ii = 0; ii < 4; ++ii) av[ii] = at[ti2 + 16 * ii][j];
            float vv[8];
            *(float4*)&vv[0] = *(const float4*)&vt[j][tv4];
            *(float4*)&vv[4] = *(const float4*)&vt[j][64 + tv4];
#pragma unroll
            for (int ii = 0; ii < 4; ++ii)
#pragma unroll
                for (int jj = 0; jj < 8; ++jj)
                    oacc[ii][jj] = fmaf(av[ii], vv[jj], oacc[ii][jj]);
        }
    }

    const float* Sp = S + ((size_t)bh * NCH + c) * (DKV * DKV);
    for (int d0 = 0; d0 < 128; d0 += 16) {
        __syncthreads();
#pragma unroll
        for (int i = 0; i < 2; ++i) {
            int q = tid + 256 * i;
            int row = q >> 5, c4 = (q & 31) * 4;
            *(float4*)&ss[row][c4] = *(const float4*)&Sp[(size_t)(d0 + row) * DKV + c4];
        }
        __syncthreads();
#pragma unroll
        for (int kk = 0; kk < 16; ++kk) {
            float qv[4];
#pragma unroll
            for (int ii = 0; ii < 4; ++ii) qv[ii] = qs[ti2 + 16 * ii][d0 + kk];
            float sv[8];
            *(float4*)&sv[0] = *(const float4*)&ss[kk][tv4];
            *(float4*)&sv[4] = *(const float4*)&ss[kk][64 + tv4];
#pragma unroll
            for (int ii = 0; ii < 4; ++ii)
#pragma unroll
                for (int jj = 0; jj < 8; ++jj)
                    oacc[ii][jj] = fmaf(qv[ii], sv[jj], oacc[ii][jj]);
        }
    }

#pragma unroll
    for (int ii = 0; ii < 4; ++ii) {
        size_t base = (rowbase + ti2 + 16 * ii) * HIDDEN + h * DKV;
        *(float4*)&O[base + tv4] = *(float4*)&oacc[ii][0];
        *(float4*)&O[base + 64 + tv4] = *(float4*)&oacc[ii][4];
    }
}

// ---------------------------------------------------------------------------
extern "C" void kernel_launch(void* const* d_in, const int* in_sizes, int n_in,
                              void* d_out, int out_size, void* d_ws, size_t ws_size,
                              hipStream_t stream)
{
    (void)in_sizes; (void)n_in; (void)out_size; (void)ws_size;
    const float* hs = (const float*)d_in[0];
    const float* wq = (const float*)d_in[1];
    const float* wk = (const float*)d_in[2];
    const float* wv = (const float*)d_in[3];
    const float* wo = (const float*)d_in[4];
    const float* cq = (const float*)d_in[5];
    const float* ck = (const float*)d_in[6];
    const float* cv = (const float*)d_in[7];
    const float* fmq_w1 = (const float*)d_in[8];
    const float* fmq_b1 = (const float*)d_in[9];
    const float* fmq_w2 = (const float*)d_in[10];
    const float* fmq_b2 = (const float*)d_in[11];
    const float* fmk_w1 = (const float*)d_in[12];
    const float* fmk_b1 = (const float*)d_in[13];
    const float* fmk_w2 = (const float*)d_in[14];
    const float* fmk_b2 = (const float*)d_in[15];
    float* out = (float*)d_out;
    float* ws = (float*)d_ws;

    const size_t SZ = (size_t)BT * HIDDEN;   // 8,388,608 floats = 32 MiB
    float* R0 = ws;            // qlin -> qf -> o16/wo16 scratch
    float* R1 = ws + SZ;       // klin -> kf
    float* R2 = ws + 2 * SZ;   // vlin -> o (attention out)
    float* R3 = ws + 3 * SZ;   // h16 (phase 1), then v (conv+silu)
    float* R4 = ws + 4 * SZ;   // w*16 (phase 1), qc, later G (spans R4..R5)
    float* R5 = ws + 5 * SZ;   // kc
    float* G = R4;             // [16][64][128][128] fp32, 64 MiB

    // ---- phase 1: cast to fp16 (aliased into regions free at this point) ----
    _Float16* h16 = (_Float16*)R3;
    _Float16* wq16 = (_Float16*)R4;
    _Float16* wk16 = wq16 + (1 << 20);
    _Float16* wv16 = wq16 + (2 << 20);
    cast_f32_f16<<<(BT * HIDDEN / 8 + 255) / 256, 256, 0, stream>>>(hs, h16, BT * HIDDEN / 8);
    cast_f32_f16<<<(HIDDEN * HIDDEN / 8 + 255) / 256, 256, 0, stream>>>(wq, wq16, HIDDEN * HIDDEN / 8);
    cast_f32_f16<<<(HIDDEN * HIDDEN / 8 + 255) / 256, 256, 0, stream>>>(wk, wk16, HIDDEN * HIDDEN / 8);
    cast_f32_f16<<<(HIDDEN * HIDDEN / 8 + 255) / 256, 256, 0, stream>>>(wv, wv16, HIDDEN * HIDDEN / 8);

    dim3 gg(HIDDEN / 128, BT / 128);         // (8, 64)
    gemm_nt_f16<<<gg, 256, 0, stream>>>(h16, wq16, R0, BT, HIDDEN, HIDDEN);
    gemm_nt_f16<<<gg, 256, 0, stream>>>(h16, wk16, R1, BT, HIDDEN, HIDDEN);
    gemm_nt_f16<<<gg, 256, 0, stream>>>(h16, wv16, R2, BT, HIDDEN, HIDDEN);

    int tot = BT * HIDDEN;
    conv_silu<<<tot / 256, 256, 0, stream>>>(R0, cq, R4);   // overwrites w*16 (done)
    conv_silu<<<tot / 256, 256, 0, stream>>>(R1, ck, R5);
    conv_silu<<<tot / 256, 256, 0, stream>>>(R2, cv, R3);   // overwrites h16 (done)

    dim3 fg(BT / 64, NHEAD);                 // (128, 8)
    fm_kernel<<<fg, 256, 0, stream>>>(R4, fmq_w1, fmq_b1, fmq_w2, fmq_b2, R0);
    fm_kernel<<<fg, 256, 0, stream>>>(R5, fmk_w1, fmk_b1, fmk_w2, fmk_b2, R1);

    dim3 ag(NCH, BATCH * NHEAD);             // (64, 16)
    ktv_kernel<<<ag, 256, 0, stream>>>(R1, R3, G);
    prefix_kernel<<<(16 * 16384) / 256, 256, 0, stream>>>(G);
    attn_kernel<<<ag, 256, 0, stream>>>(R0, R1, R3, G, R2);

    // ---- final projection in fp16 (R0/R1 free after attention) ----
    _Float16* o16 = (_Float16*)R0;
    _Float16* wo16 = (_Float16*)R1;
    cast_f32_f16<<<(BT * HIDDEN / 8 + 255) / 256, 256, 0, stream>>>(R2, o16, BT * HIDDEN / 8);
    cast_f32_f16<<<(HIDDEN * HIDDEN / 8 + 255) / 256, 256, 0, stream>>>(wo, wo16, HIDDEN * HIDDEN / 8);
    gemm_nt_f16<<<gg, 256, 0, stream>>>(o16, wo16, out, BT, HIDDEN, HIDDEN);
}

// Round 3
// 495.706 us; speedup vs baseline: 2.6859x; 1.2905x over previous
//
#include <hip/hip_runtime.h>
#include <cstdint>
#include <cstddef>

#define T_SEQ 4096
#define BATCH 2
#define HIDDEN 1024
#define NHEAD 8
#define DKV 128
#define BT (BATCH * T_SEQ)   // 8192
#define NCH 64               // chunks per batch
#define CHUNK_L 64
#define QSCALE 0.08838834764831845f
#define SCALE_P 1024.0f
#define SCALE_O 8192.0f
// combined attn epilogue factor: QSCALE * SCALE_O / SCALE_P
#define OEPS 0.7071067811865476f

typedef _Float16 half8 __attribute__((ext_vector_type(8)));
typedef float floatx4 __attribute__((ext_vector_type(4)));

union HBits { _Float16 h; unsigned short u; };

// ---------------------------------------------------------------------------
// fp32 -> fp16 cast, 8 elements/thread
// ---------------------------------------------------------------------------
__global__ void cast_f32_f16(const float* __restrict__ X, _Float16* __restrict__ Y, int n8)
{
    int idx = blockIdx.x * 256 + threadIdx.x;
    if (idx < n8) {
        float4 a = ((const float4*)X)[idx * 2];
        float4 b = ((const float4*)X)[idx * 2 + 1];
        half8 h = { (_Float16)a.x, (_Float16)a.y, (_Float16)a.z, (_Float16)a.w,
                    (_Float16)b.x, (_Float16)b.y, (_Float16)b.z, (_Float16)b.w };
        *(half8*)&Y[idx * 8] = h;
    }
}

// ---------------------------------------------------------------------------
// GEMM (NT) fp16 MFMA, fp16 out: C16[M,N] = A16[M,K] * W16[N,K]^T
// 128x128 tile, BK=32, 4 waves (2x2), 64x64/wave. global_load_lds staging.
// ---------------------------------------------------------------------------
__global__ __launch_bounds__(256) void gemm_nt_f16_h16(const _Float16* __restrict__ A,
                                                       const _Float16* __restrict__ W,
                                                       _Float16* __restrict__ C,
                                                       int M, int N, int K)
{
    __shared__ _Float16 As[128 * 32];
    __shared__ _Float16 Ws[128 * 32];
    const int bm = blockIdx.y * 128;
    const int bn = blockIdx.x * 128;
    const int tid = threadIdx.x;
    const int w = tid >> 6;
    const int l = tid & 63;
    const int wm = (w >> 1) * 64;
    const int wn = (w & 1) * 64;
    const int lane16 = l & 15;
    const int quad = l >> 4;
    const int srow = w * 16 + (l >> 2);
    const int skh = (l & 3) * 8;

    floatx4 acc[4][4];
#pragma unroll
    for (int i = 0; i < 4; ++i)
#pragma unroll
        for (int j = 0; j < 4; ++j)
            acc[i][j] = (floatx4){0.f, 0.f, 0.f, 0.f};

    for (int k0 = 0; k0 < K; k0 += 32) {
#pragma unroll
        for (int c = 0; c < 2; ++c) {
            int row = c * 64 + srow;
            const _Float16* ga = A + (size_t)(bm + row) * K + k0 + skh;
            const _Float16* gw = W + (size_t)(bn + row) * K + k0 + skh;
            __builtin_amdgcn_global_load_lds(
                (const __attribute__((address_space(1))) void*)ga,
                (__attribute__((address_space(3))) void*)(As + c * 2048 + w * 512), 16, 0, 0);
            __builtin_amdgcn_global_load_lds(
                (const __attribute__((address_space(1))) void*)gw,
                (__attribute__((address_space(3))) void*)(Ws + c * 2048 + w * 512), 16, 0, 0);
        }
        __syncthreads();

        half8 a[4], b[4];
#pragma unroll
        for (int i = 0; i < 4; ++i) {
            a[i] = *(const half8*)&As[(wm + i * 16 + lane16) * 32 + quad * 8];
            b[i] = *(const half8*)&Ws[(wn + i * 16 + lane16) * 32 + quad * 8];
        }
#pragma unroll
        for (int i = 0; i < 4; ++i)
#pragma unroll
            for (int j = 0; j < 4; ++j)
                acc[i][j] = __builtin_amdgcn_mfma_f32_16x16x32_f16(a[i], b[j], acc[i][j], 0, 0, 0);
        __syncthreads();
    }
#pragma unroll
    for (int i = 0; i < 4; ++i)
#pragma unroll
        for (int j = 0; j < 4; ++j)
#pragma unroll
            for (int r = 0; r < 4; ++r)
                C[(size_t)(bm + wm + i * 16 + quad * 4 + r) * N + bn + wn + j * 16 + lane16] =
                    (_Float16)acc[i][j][r];
}

// ---------------------------------------------------------------------------
// Same GEMM, fp32 out with scale (final projection; scale undoes SCALE_O).
// ---------------------------------------------------------------------------
__global__ __launch_bounds__(256) void gemm_nt_f16_f32(const _Float16* __restrict__ A,
                                                       const _Float16* __restrict__ W,
                                                       float* __restrict__ C,
                                                       int M, int N, int K, float scale)
{
    __shared__ _Float16 As[128 * 32];
    __shared__ _Float16 Ws[128 * 32];
    const int bm = blockIdx.y * 128;
    const int bn = blockIdx.x * 128;
    const int tid = threadIdx.x;
    const int w = tid >> 6;
    const int l = tid & 63;
    const int wm = (w >> 1) * 64;
    const int wn = (w & 1) * 64;
    const int lane16 = l & 15;
    const int quad = l >> 4;
    const int srow = w * 16 + (l >> 2);
    const int skh = (l & 3) * 8;

    floatx4 acc[4][4];
#pragma unroll
    for (int i = 0; i < 4; ++i)
#pragma unroll
        for (int j = 0; j < 4; ++j)
            acc[i][j] = (floatx4){0.f, 0.f, 0.f, 0.f};

    for (int k0 = 0; k0 < K; k0 += 32) {
#pragma unroll
        for (int c = 0; c < 2; ++c) {
            int row = c * 64 + srow;
            const _Float16* ga = A + (size_t)(bm + row) * K + k0 + skh;
            const _Float16* gw = W + (size_t)(bn + row) * K + k0 + skh;
            __builtin_amdgcn_global_load_lds(
                (const __attribute__((address_space(1))) void*)ga,
                (__attribute__((address_space(3))) void*)(As + c * 2048 + w * 512), 16, 0, 0);
            __builtin_amdgcn_global_load_lds(
                (const __attribute__((address_space(1))) void*)gw,
                (__attribute__((address_space(3))) void*)(Ws + c * 2048 + w * 512), 16, 0, 0);
        }
        __syncthreads();

        half8 a[4], b[4];
#pragma unroll
        for (int i = 0; i < 4; ++i) {
            a[i] = *(const half8*)&As[(wm + i * 16 + lane16) * 32 + quad * 8];
            b[i] = *(const half8*)&Ws[(wn + i * 16 + lane16) * 32 + quad * 8];
        }
#pragma unroll
        for (int i = 0; i < 4; ++i)
#pragma unroll
            for (int j = 0; j < 4; ++j)
                acc[i][j] = __builtin_amdgcn_mfma_f32_16x16x32_f16(a[i], b[j], acc[i][j], 0, 0, 0);
        __syncthreads();
    }
#pragma unroll
    for (int i = 0; i < 4; ++i)
#pragma unroll
        for (int j = 0; j < 4; ++j)
#pragma unroll
            for (int r = 0; r < 4; ++r)
                C[(size_t)(bm + wm + i * 16 + quad * 4 + r) * N + bn + wn + j * 16 + lane16] =
                    acc[i][j][r] * scale;
}

// ---------------------------------------------------------------------------
// Causal depthwise conv (K=4) + SiLU, fp16 in/out, natural layout.
// thread handles 8 consecutive d of one row.
// ---------------------------------------------------------------------------
__global__ void conv_silu_f16(const _Float16* __restrict__ X,
                              const float* __restrict__ Wc,
                              _Float16* __restrict__ Y)
{
    int idx = blockIdx.x * 256 + threadIdx.x;      // BT*HIDDEN/8
    int d8 = idx & 127;
    int r = idx >> 7;
    int t = r & (T_SEQ - 1);
    int d0 = d8 * 8;

    float acc[8];
    half8 x0 = *(const half8*)&X[(size_t)r * HIDDEN + d0];
#pragma unroll
    for (int e = 0; e < 8; ++e) acc[e] = (float)x0[e] * Wc[(d0 + e) * 4 + 3];
    if (t >= 1) {
        half8 x1 = *(const half8*)&X[(size_t)(r - 1) * HIDDEN + d0];
#pragma unroll
        for (int e = 0; e < 8; ++e) acc[e] = fmaf((float)x1[e], Wc[(d0 + e) * 4 + 2], acc[e]);
    }
    if (t >= 2) {
        half8 x2 = *(const half8*)&X[(size_t)(r - 2) * HIDDEN + d0];
#pragma unroll
        for (int e = 0; e < 8; ++e) acc[e] = fmaf((float)x2[e], Wc[(d0 + e) * 4 + 1], acc[e]);
    }
    if (t >= 3) {
        half8 x3 = *(const half8*)&X[(size_t)(r - 3) * HIDDEN + d0];
#pragma unroll
        for (int e = 0; e < 8; ++e) acc[e] = fmaf((float)x3[e], Wc[(d0 + e) * 4 + 0], acc[e]);
    }
    half8 o;
#pragma unroll
    for (int e = 0; e < 8; ++e) {
        float s = acc[e] / (1.f + __expf(-acc[e]));
        o[e] = (_Float16)s;
    }
    *(half8*)&Y[(size_t)r * HIDDEN + d0] = o;
}

// ---------------------------------------------------------------------------
// Conv + SiLU for V, writing TRANSPOSED: vT[b*1024 + d][t]  (fp16).
// block = (t-tile 64, d-tile 64, batch). LDS-staged transpose.
// ---------------------------------------------------------------------------
__global__ __launch_bounds__(256) void conv_silu_T(const _Float16* __restrict__ X,
                                                   const float* __restrict__ Wc,
                                                   _Float16* __restrict__ VT)
{
    __shared__ _Float16 xs[67 * 64];
    const int t0 = blockIdx.x * 64;
    const int dt = blockIdx.y * 64;
    const int z = blockIdx.z;
    const int tid = threadIdx.x;

    // stage 67 rows (t0-3 .. t0+63) x 64 d
#pragma unroll
    for (int i = 0; i < 3; ++i) {
        int p = tid + 256 * i;
        if (p < 536) {
            int row = p >> 3, d8 = (p & 7) * 8;
            int t = t0 - 3 + row;
            half8 v;
            if (t >= 0)
                v = *(const half8*)&X[((size_t)z * T_SEQ + t) * HIDDEN + dt + d8];
            else
                v = (half8){0, 0, 0, 0, 0, 0, 0, 0};
            *(half8*)&xs[row * 64 + d8] = v;
        }
    }
    __syncthreads();

    const int d = tid & 63;
    const int dg = dt + d;
    float4 w = *(const float4*)&Wc[dg * 4];
#pragma unroll
    for (int u = 0; u < 2; ++u) {
        int tg = (tid >> 6) + u * 4;   // 0..7
        half8 o;
#pragma unroll
        for (int s = 0; s < 8; ++s) {
            int base = (tg * 8 + s + 3) * 64 + d;   // row t in xs is (t - t0 + 3)
            float acc = (float)xs[base] * w.w
                      + (float)xs[base - 64] * w.z
                      + (float)xs[base - 128] * w.y
                      + (float)xs[base - 192] * w.x;
            o[s] = (_Float16)(acc / (1.f + __expf(-acc)));
        }
        *(half8*)&VT[((size_t)z * HIDDEN + dg) * T_SEQ + t0 + tg * 8] = o;
    }
}

// ---------------------------------------------------------------------------
// Feature map, MFMA: OUT16[t, h*128+e] = (X@W1^T + b1) * (X@W2^T + b2)
// block = (64 rows, head). X staged in LDS (k-slabbed), W frags from global.
// ---------------------------------------------------------------------------
__global__ __launch_bounds__(256) void fm_mfma(const _Float16* __restrict__ X,
                                               const _Float16* __restrict__ W1h,
                                               const float* __restrict__ B1,
                                               const _Float16* __restrict__ W2h,
                                               const float* __restrict__ B2,
                                               _Float16* __restrict__ OUT)
{
    __shared__ _Float16 xs[4 * 64 * 32];   // [kstep][row][32]
    const int t0 = blockIdx.x * 64;
    const int h = blockIdx.y;
    const int tid = threadIdx.x;
    const int w = tid >> 6;
    const int l = tid & 63;
    const int lane16 = l & 15;
    const int quad = l >> 4;

    // wave w stages kstep slab w: rows in groups of 16
#pragma unroll
    for (int c = 0; c < 4; ++c) {
        int row = c * 16 + (l >> 2);
        const _Float16* g = X + (size_t)(t0 + row) * HIDDEN + h * DKV + w * 32 + (l & 3) * 8;
        __builtin_amdgcn_global_load_lds(
            (const __attribute__((address_space(1))) void*)g,
            (__attribute__((address_space(3))) void*)(xs + w * 2048 + c * 512), 16, 0, 0);
    }
    __syncthreads();

    floatx4 acc1[4][2], acc2[4][2];
#pragma unroll
    for (int i = 0; i < 4; ++i)
#pragma unroll
        for (int j = 0; j < 2; ++j) {
            acc1[i][j] = (floatx4){0.f, 0.f, 0.f, 0.f};
            acc2[i][j] = (floatx4){0.f, 0.f, 0.f, 0.f};
        }

#pragma unroll
    for (int s = 0; s < 4; ++s) {
        half8 a[4];
#pragma unroll
        for (int mt = 0; mt < 4; ++mt)
            a[mt] = *(const half8*)&xs[s * 2048 + (mt * 16 + lane16) * 32 + quad * 8];
#pragma unroll
        for (int nt = 0; nt < 2; ++nt) {
            int e = w * 32 + nt * 16 + lane16;
            half8 b1 = *(const half8*)&W1h[(size_t)e * DKV + s * 32 + quad * 8];
            half8 b2 = *(const half8*)&W2h[(size_t)e * DKV + s * 32 + quad * 8];
#pragma unroll
            for (int mt = 0; mt < 4; ++mt) {
                acc1[mt][nt] = __builtin_amdgcn_mfma_f32_16x16x32_f16(a[mt], b1, acc1[mt][nt], 0, 0, 0);
                acc2[mt][nt] = __builtin_amdgcn_mfma_f32_16x16x32_f16(a[mt], b2, acc2[mt][nt], 0, 0, 0);
            }
        }
    }

#pragma unroll
    for (int nt = 0; nt < 2; ++nt) {
        int e = w * 32 + nt * 16 + lane16;
        float b1v = B1[e], b2v = B2[e];
#pragma unroll
        for (int mt = 0; mt < 4; ++mt)
#pragma unroll
            for (int r = 0; r < 4; ++r) {
                float o = (acc1[mt][nt][r] + b1v) * (acc2[mt][nt][r] + b2v);
                OUT[(size_t)(t0 + mt * 16 + quad * 4 + r) * HIDDEN + h * DKV + e] = (_Float16)o;
            }
    }
}

// ---------------------------------------------------------------------------
// Per-chunk S^T[dv][dk] = sum_j V[j][dv] K[j][dk], MFMA.
// A = vT (natural), B = K^T via LDS transpose of kf. Output fp32 G natural.
// ---------------------------------------------------------------------------
__global__ __launch_bounds__(256) void ktv_mfma(const _Float16* __restrict__ Kf,
                                                const _Float16* __restrict__ VT,
                                                float* __restrict__ G)
{
    __shared__ _Float16 kt[128 * 72];   // [dk][72 (64 j + pad)]
    const int c = blockIdx.x;
    const int bh = blockIdx.y;
    const int b = bh >> 3, h = bh & 7;
    const int tid = threadIdx.x;
    const int w = tid >> 6;
    const int l = tid & 63;
    const int lane16 = l & 15;
    const int quad = l >> 4;
    const size_t rowbase = (size_t)b * T_SEQ + (size_t)c * CHUNK_L;

    // transpose-stage K chunk: thread (dk-oct = tid>>4, j-quad = tid&15)
    {
        const int dk0 = (tid >> 4) * 8;
        const int jb = (tid & 15) * 4;
        half8 r0 = *(const half8*)&Kf[(rowbase + jb + 0) * HIDDEN + h * DKV + dk0];
        half8 r1 = *(const half8*)&Kf[(rowbase + jb + 1) * HIDDEN + h * DKV + dk0];
        half8 r2 = *(const half8*)&Kf[(rowbase + jb + 2) * HIDDEN + h * DKV + dk0];
        half8 r3 = *(const half8*)&Kf[(rowbase + jb + 3) * HIDDEN + h * DKV + dk0];
#pragma unroll
        for (int dk = 0; dk < 8; ++dk) {
            HBits a0, a1, a2, a3;
            a0.h = r0[dk]; a1.h = r1[dk]; a2.h = r2[dk]; a3.h = r3[dk];
            unsigned int lo = ((unsigned int)a1.u << 16) | a0.u;
            unsigned int hi = ((unsigned int)a3.u << 16) | a2.u;
            *(unsigned int*)&kt[(dk0 + dk) * 72 + jb] = lo;
            *(unsigned int*)&kt[(dk0 + dk) * 72 + jb + 2] = hi;
        }
    }
    __syncthreads();

    const int m0 = (w >> 1) * 64;   // dv
    const int n0 = (w & 1) * 64;    // dk
    floatx4 acc[4][4];
#pragma unroll
    for (int i = 0; i < 4; ++i)
#pragma unroll
        for (int j = 0; j < 4; ++j)
            acc[i][j] = (floatx4){0.f, 0.f, 0.f, 0.f};

#pragma unroll
    for (int s = 0; s < 2; ++s) {
        half8 a[4], bb[4];
#pragma unroll
        for (int mt = 0; mt < 4; ++mt) {
            int dv = m0 + mt * 16 + lane16;
            a[mt] = *(const half8*)&VT[((size_t)bh * DKV + dv) * T_SEQ + c * CHUNK_L + s * 32 + quad * 8];
        }
#pragma unroll
        for (int nt = 0; nt < 4; ++nt)
            bb[nt] = *(const half8*)&kt[(n0 + nt * 16 + lane16) * 72 + s * 32 + quad * 8];
#pragma unroll
        for (int mt = 0; mt < 4; ++mt)
#pragma unroll
            for (int nt = 0; nt < 4; ++nt)
                acc[mt][nt] = __builtin_amdgcn_mfma_f32_16x16x32_f16(a[mt], bb[nt], acc[mt][nt], 0, 0, 0);
    }

    float* Gp = G + ((size_t)bh * NCH + c) * (DKV * DKV);
#pragma unroll
    for (int mt = 0; mt < 4; ++mt)
#pragma unroll
        for (int nt = 0; nt < 4; ++nt)
#pragma unroll
            for (int r = 0; r < 4; ++r)
                Gp[(size_t)(m0 + mt * 16 + quad * 4 + r) * DKV + n0 + nt * 16 + lane16] =
                    acc[mt][nt][r];
}

// ---------------------------------------------------------------------------
// Exclusive prefix over chunks; G fp32 in -> Gh fp16 out (scaled by SCALE_P).
// ---------------------------------------------------------------------------
__global__ void prefix_kernel(const float* __restrict__ G, _Float16* __restrict__ Gh)
{
    int idx = blockIdx.x * 256 + threadIdx.x;   // 16 * 16384
    int bh = idx >> 14;
    int e = idx & 16383;
    const float* p = G + (size_t)bh * NCH * 16384 + e;
    _Float16* q = Gh + (size_t)bh * NCH * 16384 + e;
    float run = 0.f;
#pragma unroll
    for (int c = 0; c < NCH; ++c) {
        q[(size_t)c * 16384] = (_Float16)(run * SCALE_P);
        run += p[(size_t)c * 16384];
    }
}

// ---------------------------------------------------------------------------
// Attention per chunk, MFMA:
//   P = tril(Q K^T) * SCALE_P -> LDS fp16
//   O = (P @ V + Q @ S^T_scaled) * OEPS  -> fp16 natural [t][d]
// ---------------------------------------------------------------------------
__global__ __launch_bounds__(256) void attn_mfma(const _Float16* __restrict__ Qf,
                                                 const _Float16* __restrict__ Kf,
                                                 const _Float16* __restrict__ VT,
                                                 const _Float16* __restrict__ Gh,
                                                 _Float16* __restrict__ O)
{
    __shared__ _Float16 ps[2 * 64 * 32];   // [jstep][i][32]
    const int c = blockIdx.x;
    const int bh = blockIdx.y;
    const int b = bh >> 3, h = bh & 7;
    const int tid = threadIdx.x;
    const int w = tid >> 6;
    const int l = tid & 63;
    const int lane16 = l & 15;
    const int quad = l >> 4;
    const size_t rowbase = (size_t)b * T_SEQ + (size_t)c * CHUNK_L;

    // ---- phase 1: QK^T (64x64x128), wave grid 2x2 ----
    {
        const int m0 = (w >> 1) * 32;
        const int n0 = (w & 1) * 32;
        floatx4 aq[2][2];
#pragma unroll
        for (int i = 0; i < 2; ++i)
#pragma unroll
            for (int j = 0; j < 2; ++j)
                aq[i][j] = (floatx4){0.f, 0.f, 0.f, 0.f};
#pragma unroll
        for (int s = 0; s < 4; ++s) {
            half8 a[2], bb[2];
#pragma unroll
            for (int mt = 0; mt < 2; ++mt)
                a[mt] = *(const half8*)&Qf[(rowbase + m0 + mt * 16 + lane16) * HIDDEN +
                                           h * DKV + s * 32 + quad * 8];
#pragma unroll
            for (int nt = 0; nt < 2; ++nt)
                bb[nt] = *(const half8*)&Kf[(rowbase + n0 + nt * 16 + lane16) * HIDDEN +
                                            h * DKV + s * 32 + quad * 8];
#pragma unroll
            for (int mt = 0; mt < 2; ++mt)
#pragma unroll
                for (int nt = 0; nt < 2; ++nt)
                    aq[mt][nt] = __builtin_amdgcn_mfma_f32_16x16x32_f16(a[mt], bb[nt], aq[mt][nt], 0, 0, 0);
        }
#pragma unroll
        for (int mt = 0; mt < 2; ++mt)
#pragma unroll
            for (int nt = 0; nt < 2; ++nt) {
                int j = n0 + nt * 16 + lane16;
#pragma unroll
                for (int r = 0; r < 4; ++r) {
                    int i = m0 + mt * 16 + quad * 4 + r;
                    float v = (j <= i) ? aq[mt][nt][r] * SCALE_P : 0.f;
                    ps[(j >> 5) * 2048 + i * 32 + (j & 31)] = (_Float16)v;
                }
            }
    }
    __syncthreads();

    // ---- phase 2: O = P@V + Q@S^T ; wave grid 1x4 over dv ----
    const int n0o = w * 32;
    floatx4 accO[4][2];
#pragma unroll
    for (int i = 0; i < 4; ++i)
#pragma unroll
        for (int j = 0; j < 2; ++j)
            accO[i][j] = (floatx4){0.f, 0.f, 0.f, 0.f};

    // P @ V   (contract j, 2 ksteps)
#pragma unroll
    for (int s = 0; s < 2; ++s) {
        half8 a[4], bb[2];
#pragma unroll
        for (int mt = 0; mt < 4; ++mt)
            a[mt] = *(const half8*)&ps[s * 2048 + (mt * 16 + lane16) * 32 + quad * 8];
#pragma unroll
        for (int nt = 0; nt < 2; ++nt) {
            int dv = n0o + nt * 16 + lane16;
            bb[nt] = *(const half8*)&VT[((size_t)bh * DKV + dv) * T_SEQ + c * CHUNK_L + s * 32 + quad * 8];
        }
#pragma unroll
        for (int mt = 0; mt < 4; ++mt)
#pragma unroll
            for (int nt = 0; nt < 2; ++nt)
                accO[mt][nt] = __builtin_amdgcn_mfma_f32_16x16x32_f16(a[mt], bb[nt], accO[mt][nt], 0, 0, 0);
    }

    // Q @ S^T  (contract dk, 4 ksteps)
    const _Float16* gh = Gh + ((size_t)bh * NCH + c) * (DKV * DKV);
#pragma unroll
    for (int s = 0; s < 4; ++s) {
        half8 a[4], bb[2];
#pragma unroll
        for (int mt = 0; mt < 4; ++mt)
            a[mt] = *(const half8*)&Qf[(rowbase + mt * 16 + lane16) * HIDDEN +
                                       h * DKV + s * 32 + quad * 8];
#pragma unroll
        for (int nt = 0; nt < 2; ++nt) {
            int dv = n0o + nt * 16 + lane16;
            bb[nt] = *(const half8*)&gh[(size_t)dv * DKV + s * 32 + quad * 8];
        }
#pragma unroll
        for (int mt = 0; mt < 4; ++mt)
#pragma unroll
            for (int nt = 0; nt < 2; ++nt)
                accO[mt][nt] = __builtin_amdgcn_mfma_f32_16x16x32_f16(a[mt], bb[nt], accO[mt][nt], 0, 0, 0);
    }

#pragma unroll
    for (int mt = 0; mt < 4; ++mt)
#pragma unroll
        for (int nt = 0; nt < 2; ++nt)
#pragma unroll
            for (int r = 0; r < 4; ++r)
                O[(rowbase + mt * 16 + quad * 4 + r) * HIDDEN + h * DKV + n0o + nt * 16 + lane16] =
                    (_Float16)(accO[mt][nt][r] * OEPS);
}

// ---------------------------------------------------------------------------
extern "C" void kernel_launch(void* const* d_in, const int* in_sizes, int n_in,
                              void* d_out, int out_size, void* d_ws, size_t ws_size,
                              hipStream_t stream)
{
    (void)in_sizes; (void)n_in; (void)out_size; (void)ws_size;
    const float* hs = (const float*)d_in[0];
    const float* wq = (const float*)d_in[1];
    const float* wk = (const float*)d_in[2];
    const float* wv = (const float*)d_in[3];
    const float* wo = (const float*)d_in[4];
    const float* cq = (const float*)d_in[5];
    const float* ck = (const float*)d_in[6];
    const float* cv = (const float*)d_in[7];
    const float* fmq_w1 = (const float*)d_in[8];
    const float* fmq_b1 = (const float*)d_in[9];
    const float* fmq_w2 = (const float*)d_in[10];
    const float* fmq_b2 = (const float*)d_in[11];
    const float* fmk_w1 = (const float*)d_in[12];
    const float* fmk_b1 = (const float*)d_in[13];
    const float* fmk_w2 = (const float*)d_in[14];
    const float* fmk_b2 = (const float*)d_in[15];
    float* out = (float*)d_out;
    char* ws = (char*)d_ws;

    const size_t MB = 1024 * 1024;
    // byte-offset regions (total 192 MiB)
    _Float16* h16    = (_Float16*)(ws + 0);          // 16 MB; dead after lin gemms -> qf16
    _Float16* qf16   = (_Float16*)(ws + 0);
    _Float16* wq16   = (_Float16*)(ws + 16 * MB);    // weight block, alive whole run
    _Float16* wk16   = wq16 + (1 << 20);
    _Float16* wv16   = wq16 + (2 << 20);
    _Float16* wo16   = wq16 + (3 << 20);
    _Float16* fmw    = wq16 + (4 << 20);             // 4 x 16384 halfs
    _Float16* qlin16 = (_Float16*)(ws + 32 * MB);    // dead after conv -> kf16
    _Float16* kf16   = (_Float16*)(ws + 32 * MB);
    _Float16* klin16 = (_Float16*)(ws + 48 * MB);    // dead after conv -> O16
    _Float16* O16    = (_Float16*)(ws + 48 * MB);
    _Float16* vlin16 = (_Float16*)(ws + 64 * MB);    // dead after conv-v
    _Float16* Gh     = (_Float16*)(ws + 64 * MB);    // 32 MB, spans vlin16+qc16
    _Float16* qc16   = (_Float16*)(ws + 80 * MB);    // dead after fm_q
    _Float16* kc16   = (_Float16*)(ws + 96 * MB);    // dead after fm_k
    _Float16* vT     = (_Float16*)(ws + 112 * MB);   // alive till attn
    float*    G      = (float*)(ws + 128 * MB);      // 64 MB fp32

    // ---- casts ----
    cast_f32_f16<<<4096, 256, 0, stream>>>(hs, h16, BT * HIDDEN / 8);
    cast_f32_f16<<<512, 256, 0, stream>>>(wq, wq16, HIDDEN * HIDDEN / 8);
    cast_f32_f16<<<512, 256, 0, stream>>>(wk, wk16, HIDDEN * HIDDEN / 8);
    cast_f32_f16<<<512, 256, 0, stream>>>(wv, wv16, HIDDEN * HIDDEN / 8);
    cast_f32_f16<<<512, 256, 0, stream>>>(wo, wo16, HIDDEN * HIDDEN / 8);
    cast_f32_f16<<<8, 256, 0, stream>>>(fmq_w1, fmw, DKV * DKV / 8);
    cast_f32_f16<<<8, 256, 0, stream>>>(fmq_w2, fmw + 16384, DKV * DKV / 8);
    cast_f32_f16<<<8, 256, 0, stream>>>(fmk_w1, fmw + 2 * 16384, DKV * DKV / 8);
    cast_f32_f16<<<8, 256, 0, stream>>>(fmk_w2, fmw + 3 * 16384, DKV * DKV / 8);

    // ---- input projections ----
    dim3 gg(HIDDEN / 128, BT / 128);
    gemm_nt_f16_h16<<<gg, 256, 0, stream>>>(h16, wq16, qlin16, BT, HIDDEN, HIDDEN);
    gemm_nt_f16_h16<<<gg, 256, 0, stream>>>(h16, wk16, klin16, BT, HIDDEN, HIDDEN);
    gemm_nt_f16_h16<<<gg, 256, 0, stream>>>(h16, wv16, vlin16, BT, HIDDEN, HIDDEN);

    // ---- conv + silu ----
    conv_silu_f16<<<BT * HIDDEN / 8 / 256, 256, 0, stream>>>(qlin16, cq, qc16);
    conv_silu_f16<<<BT * HIDDEN / 8 / 256, 256, 0, stream>>>(klin16, ck, kc16);
    dim3 cg(T_SEQ / 64, HIDDEN / 64, BATCH);
    conv_silu_T<<<cg, 256, 0, stream>>>(vlin16, cv, vT);

    // ---- feature maps ----
    dim3 fg(BT / 64, NHEAD);
    fm_mfma<<<fg, 256, 0, stream>>>(qc16, fmw, fmq_b1, fmw + 16384, fmq_b2, qf16);
    fm_mfma<<<fg, 256, 0, stream>>>(kc16, fmw + 2 * 16384, fmk_b1, fmw + 3 * 16384, fmk_b2, kf16);

    // ---- chunked linear attention ----
    dim3 ag(NCH, BATCH * NHEAD);
    ktv_mfma<<<ag, 256, 0, stream>>>(kf16, vT, G);
    prefix_kernel<<<(16 * 16384) / 256, 256, 0, stream>>>(G, Gh);
    attn_mfma<<<ag, 256, 0, stream>>>(qf16, kf16, vT, Gh, O16);

    // ---- output projection (undo SCALE_O) ----
    gemm_nt_f16_f32<<<gg, 256, 0, stream>>>(O16, wo16, out, BT, HIDDEN, HIDDEN, 1.0f / SCALE_O);
}

// Round 4
// 388.627 us; speedup vs baseline: 3.4260x; 1.2755x over previous
//
#include <hip/hip_runtime.h>
#include <cstdint>
#include <cstddef>

#define T_SEQ 4096
#define BATCH 2
#define HIDDEN 1024
#define NHEAD 8
#define DKV 128
#define BT (BATCH * T_SEQ)   // 8192
#define NCH 64               // chunks per batch
#define CHUNK_L 64
#define QSCALE 0.08838834764831845f
#define SCALE_P 1024.0f
#define SCALE_O 8192.0f
// combined attn epilogue factor: QSCALE * SCALE_O / SCALE_P
#define OEPS 0.7071067811865476f

typedef _Float16 half8 __attribute__((ext_vector_type(8)));
typedef float floatx4 __attribute__((ext_vector_type(4)));

union HBits { _Float16 h; unsigned short u; };

// ---------------------------------------------------------------------------
// fp32 -> fp16 cast, 8 elements/thread
// ---------------------------------------------------------------------------
__global__ void cast_f32_f16(const float* __restrict__ X, _Float16* __restrict__ Y, int n8)
{
    int idx = blockIdx.x * 256 + threadIdx.x;
    if (idx < n8) {
        float4 a = ((const float4*)X)[idx * 2];
        float4 b = ((const float4*)X)[idx * 2 + 1];
        half8 h = { (_Float16)a.x, (_Float16)a.y, (_Float16)a.z, (_Float16)a.w,
                    (_Float16)b.x, (_Float16)b.y, (_Float16)b.z, (_Float16)b.w };
        *(half8*)&Y[idx * 8] = h;
    }
}

// 4 tensors in one launch; blockIdx.y selects tensor. All have n8 vec8-groups.
__global__ void cast4_f32_f16(const float* __restrict__ A, const float* __restrict__ B,
                              const float* __restrict__ C, const float* __restrict__ D,
                              _Float16* __restrict__ a, _Float16* __restrict__ b,
                              _Float16* __restrict__ c, _Float16* __restrict__ d, int n8)
{
    int sel = blockIdx.y;
    const float* src = (sel == 0) ? A : (sel == 1) ? B : (sel == 2) ? C : D;
    _Float16* dst = (sel == 0) ? a : (sel == 1) ? b : (sel == 2) ? c : d;
    int idx = blockIdx.x * 256 + threadIdx.x;
    if (idx < n8) {
        float4 u = ((const float4*)src)[idx * 2];
        float4 v = ((const float4*)src)[idx * 2 + 1];
        half8 h = { (_Float16)u.x, (_Float16)u.y, (_Float16)u.z, (_Float16)u.w,
                    (_Float16)v.x, (_Float16)v.y, (_Float16)v.z, (_Float16)v.w };
        *(half8*)&dst[idx * 8] = h;
    }
}

// ---------------------------------------------------------------------------
// GEMM (NT) fp16 MFMA, fp16 out: C16[M,N] = A16[M,K] * W16[N,K]^T
// 128x128 tile, BK=32, 4 waves (2x2), 64x64/wave. global_load_lds staging.
// ---------------------------------------------------------------------------
__global__ __launch_bounds__(256) void gemm_nt_f16_h16(const _Float16* __restrict__ A,
                                                       const _Float16* __restrict__ W,
                                                       _Float16* __restrict__ C,
                                                       int M, int N, int K)
{
    __shared__ _Float16 As[128 * 32];
    __shared__ _Float16 Ws[128 * 32];
    const int bm = blockIdx.y * 128;
    const int bn = blockIdx.x * 128;
    const int tid = threadIdx.x;
    const int w = tid >> 6;
    const int l = tid & 63;
    const int wm = (w >> 1) * 64;
    const int wn = (w & 1) * 64;
    const int lane16 = l & 15;
    const int quad = l >> 4;
    const int srow = w * 16 + (l >> 2);
    const int skh = (l & 3) * 8;

    floatx4 acc[4][4];
#pragma unroll
    for (int i = 0; i < 4; ++i)
#pragma unroll
        for (int j = 0; j < 4; ++j)
            acc[i][j] = (floatx4){0.f, 0.f, 0.f, 0.f};

    for (int k0 = 0; k0 < K; k0 += 32) {
#pragma unroll
        for (int c = 0; c < 2; ++c) {
            int row = c * 64 + srow;
            const _Float16* ga = A + (size_t)(bm + row) * K + k0 + skh;
            const _Float16* gw = W + (size_t)(bn + row) * K + k0 + skh;
            __builtin_amdgcn_global_load_lds(
                (const __attribute__((address_space(1))) void*)ga,
                (__attribute__((address_space(3))) void*)(As + c * 2048 + w * 512), 16, 0, 0);
            __builtin_amdgcn_global_load_lds(
                (const __attribute__((address_space(1))) void*)gw,
                (__attribute__((address_space(3))) void*)(Ws + c * 2048 + w * 512), 16, 0, 0);
        }
        __syncthreads();

        half8 a[4], b[4];
#pragma unroll
        for (int i = 0; i < 4; ++i) {
            a[i] = *(const half8*)&As[(wm + i * 16 + lane16) * 32 + quad * 8];
            b[i] = *(const half8*)&Ws[(wn + i * 16 + lane16) * 32 + quad * 8];
        }
#pragma unroll
        for (int i = 0; i < 4; ++i)
#pragma unroll
            for (int j = 0; j < 4; ++j)
                acc[i][j] = __builtin_amdgcn_mfma_f32_16x16x32_f16(a[i], b[j], acc[i][j], 0, 0, 0);
        __syncthreads();
    }
#pragma unroll
    for (int i = 0; i < 4; ++i)
#pragma unroll
        for (int j = 0; j < 4; ++j)
#pragma unroll
            for (int r = 0; r < 4; ++r)
                C[(size_t)(bm + wm + i * 16 + quad * 4 + r) * N + bn + wn + j * 16 + lane16] =
                    (_Float16)acc[i][j][r];
}

// ---------------------------------------------------------------------------
// Same GEMM, fp32 out with scale (final projection; scale undoes SCALE_O).
// ---------------------------------------------------------------------------
__global__ __launch_bounds__(256) void gemm_nt_f16_f32(const _Float16* __restrict__ A,
                                                       const _Float16* __restrict__ W,
                                                       float* __restrict__ C,
                                                       int M, int N, int K, float scale)
{
    __shared__ _Float16 As[128 * 32];
    __shared__ _Float16 Ws[128 * 32];
    const int bm = blockIdx.y * 128;
    const int bn = blockIdx.x * 128;
    const int tid = threadIdx.x;
    const int w = tid >> 6;
    const int l = tid & 63;
    const int wm = (w >> 1) * 64;
    const int wn = (w & 1) * 64;
    const int lane16 = l & 15;
    const int quad = l >> 4;
    const int srow = w * 16 + (l >> 2);
    const int skh = (l & 3) * 8;

    floatx4 acc[4][4];
#pragma unroll
    for (int i = 0; i < 4; ++i)
#pragma unroll
        for (int j = 0; j < 4; ++j)
            acc[i][j] = (floatx4){0.f, 0.f, 0.f, 0.f};

    for (int k0 = 0; k0 < K; k0 += 32) {
#pragma unroll
        for (int c = 0; c < 2; ++c) {
            int row = c * 64 + srow;
            const _Float16* ga = A + (size_t)(bm + row) * K + k0 + skh;
            const _Float16* gw = W + (size_t)(bn + row) * K + k0 + skh;
            __builtin_amdgcn_global_load_lds(
                (const __attribute__((address_space(1))) void*)ga,
                (__attribute__((address_space(3))) void*)(As + c * 2048 + w * 512), 16, 0, 0);
            __builtin_amdgcn_global_load_lds(
                (const __attribute__((address_space(1))) void*)gw,
                (__attribute__((address_space(3))) void*)(Ws + c * 2048 + w * 512), 16, 0, 0);
        }
        __syncthreads();

        half8 a[4], b[4];
#pragma unroll
        for (int i = 0; i < 4; ++i) {
            a[i] = *(const half8*)&As[(wm + i * 16 + lane16) * 32 + quad * 8];
            b[i] = *(const half8*)&Ws[(wn + i * 16 + lane16) * 32 + quad * 8];
        }
#pragma unroll
        for (int i = 0; i < 4; ++i)
#pragma unroll
            for (int j = 0; j < 4; ++j)
                acc[i][j] = __builtin_amdgcn_mfma_f32_16x16x32_f16(a[i], b[j], acc[i][j], 0, 0, 0);
        __syncthreads();
    }
#pragma unroll
    for (int i = 0; i < 4; ++i)
#pragma unroll
        for (int j = 0; j < 4; ++j)
#pragma unroll
            for (int r = 0; r < 4; ++r)
                C[(size_t)(bm + wm + i * 16 + quad * 4 + r) * N + bn + wn + j * 16 + lane16] =
                    acc[i][j][r] * scale;
}

// ---------------------------------------------------------------------------
// Causal depthwise conv (K=4) + SiLU, column-walking: thread owns 8 channels,
// loads weights ONCE, streams CSTRIPE=16 rows with a 3-row sliding window.
// ---------------------------------------------------------------------------
#define CSTRIPE 16
__global__ __launch_bounds__(256) void conv_silu_col(const _Float16* __restrict__ X,
                                                     const float* __restrict__ Wc,
                                                     _Float16* __restrict__ Y)
{
    int gid = blockIdx.x * 256 + threadIdx.x;     // 128 chunks x (BT/16) stripes
    int c = gid & 127;
    int sg = gid >> 7;
    int r0 = sg * CSTRIPE;
    int tloc = r0 & (T_SEQ - 1);
    int d0 = c * 8;

    float w0[8], w1[8], w2[8], w3[8];
#pragma unroll
    for (int e = 0; e < 8; ++e) {
        float4 wv = *(const float4*)&Wc[(d0 + e) * 4];
        w0[e] = wv.x; w1[e] = wv.y; w2[e] = wv.z; w3[e] = wv.w;
    }

    half8 xm1 = {0,0,0,0,0,0,0,0}, xm2 = xm1, xm3 = xm1;
    if (tloc >= 1) xm1 = *(const half8*)&X[(size_t)(r0 - 1) * HIDDEN + d0];
    if (tloc >= 2) xm2 = *(const half8*)&X[(size_t)(r0 - 2) * HIDDEN + d0];
    if (tloc >= 3) xm3 = *(const half8*)&X[(size_t)(r0 - 3) * HIDDEN + d0];

    for (int i = 0; i < CSTRIPE; ++i) {
        half8 x0 = *(const half8*)&X[(size_t)(r0 + i) * HIDDEN + d0];
        half8 o;
#pragma unroll
        for (int e = 0; e < 8; ++e) {
            float acc = fmaf((float)x0[e], w3[e],
                        fmaf((float)xm1[e], w2[e],
                        fmaf((float)xm2[e], w1[e], (float)xm3[e] * w0[e])));
            o[e] = (_Float16)(acc / (1.f + __expf(-acc)));
        }
        *(half8*)&Y[(size_t)(r0 + i) * HIDDEN + d0] = o;
        xm3 = xm2; xm2 = xm1; xm1 = x0;
    }
}

// ---------------------------------------------------------------------------
// Conv + SiLU for V, writing TRANSPOSED: vT[b*1024 + d][t]  (fp16).
// ---------------------------------------------------------------------------
__global__ __launch_bounds__(256) void conv_silu_T(const _Float16* __restrict__ X,
                                                   const float* __restrict__ Wc,
                                                   _Float16* __restrict__ VT)
{
    __shared__ _Float16 xs[67 * 64];
    const int t0 = blockIdx.x * 64;
    const int dt = blockIdx.y * 64;
    const int z = blockIdx.z;
    const int tid = threadIdx.x;

#pragma unroll
    for (int i = 0; i < 3; ++i) {
        int p = tid + 256 * i;
        if (p < 536) {
            int row = p >> 3, d8 = (p & 7) * 8;
            int t = t0 - 3 + row;
            half8 v;
            if (t >= 0)
                v = *(const half8*)&X[((size_t)z * T_SEQ + t) * HIDDEN + dt + d8];
            else
                v = (half8){0, 0, 0, 0, 0, 0, 0, 0};
            *(half8*)&xs[row * 64 + d8] = v;
        }
    }
    __syncthreads();

    const int d = tid & 63;
    const int dg = dt + d;
    float4 w = *(const float4*)&Wc[dg * 4];
#pragma unroll
    for (int u = 0; u < 2; ++u) {
        int tg = (tid >> 6) + u * 4;
        half8 o;
#pragma unroll
        for (int s = 0; s < 8; ++s) {
            int base = (tg * 8 + s + 3) * 64 + d;
            float acc = (float)xs[base] * w.w
                      + (float)xs[base - 64] * w.z
                      + (float)xs[base - 128] * w.y
                      + (float)xs[base - 192] * w.x;
            o[s] = (_Float16)(acc / (1.f + __expf(-acc)));
        }
        *(half8*)&VT[((size_t)z * HIDDEN + dg) * T_SEQ + t0 + tg * 8] = o;
    }
}

// ---------------------------------------------------------------------------
// Feature map, MFMA: OUT16[t, h*128+e] = (X@W1^T + b1) * (X@W2^T + b2)
// ---------------------------------------------------------------------------
__global__ __launch_bounds__(256) void fm_mfma(const _Float16* __restrict__ X,
                                               const _Float16* __restrict__ W1h,
                                               const float* __restrict__ B1,
                                               const _Float16* __restrict__ W2h,
                                               const float* __restrict__ B2,
                                               _Float16* __restrict__ OUT)
{
    __shared__ _Float16 xs[4 * 64 * 32];   // [kstep][row][32]
    const int t0 = blockIdx.x * 64;
    const int h = blockIdx.y;
    const int tid = threadIdx.x;
    const int w = tid >> 6;
    const int l = tid & 63;
    const int lane16 = l & 15;
    const int quad = l >> 4;

#pragma unroll
    for (int c = 0; c < 4; ++c) {
        int row = c * 16 + (l >> 2);
        const _Float16* g = X + (size_t)(t0 + row) * HIDDEN + h * DKV + w * 32 + (l & 3) * 8;
        __builtin_amdgcn_global_load_lds(
            (const __attribute__((address_space(1))) void*)g,
            (__attribute__((address_space(3))) void*)(xs + w * 2048 + c * 512), 16, 0, 0);
    }
    __syncthreads();

    floatx4 acc1[4][2], acc2[4][2];
#pragma unroll
    for (int i = 0; i < 4; ++i)
#pragma unroll
        for (int j = 0; j < 2; ++j) {
            acc1[i][j] = (floatx4){0.f, 0.f, 0.f, 0.f};
            acc2[i][j] = (floatx4){0.f, 0.f, 0.f, 0.f};
        }

#pragma unroll
    for (int s = 0; s < 4; ++s) {
        half8 a[4];
#pragma unroll
        for (int mt = 0; mt < 4; ++mt)
            a[mt] = *(const half8*)&xs[s * 2048 + (mt * 16 + lane16) * 32 + quad * 8];
#pragma unroll
        for (int nt = 0; nt < 2; ++nt) {
            int e = w * 32 + nt * 16 + lane16;
            half8 b1 = *(const half8*)&W1h[(size_t)e * DKV + s * 32 + quad * 8];
            half8 b2 = *(const half8*)&W2h[(size_t)e * DKV + s * 32 + quad * 8];
#pragma unroll
            for (int mt = 0; mt < 4; ++mt) {
                acc1[mt][nt] = __builtin_amdgcn_mfma_f32_16x16x32_f16(a[mt], b1, acc1[mt][nt], 0, 0, 0);
                acc2[mt][nt] = __builtin_amdgcn_mfma_f32_16x16x32_f16(a[mt], b2, acc2[mt][nt], 0, 0, 0);
            }
        }
    }

#pragma unroll
    for (int nt = 0; nt < 2; ++nt) {
        int e = w * 32 + nt * 16 + lane16;
        float b1v = B1[e], b2v = B2[e];
#pragma unroll
        for (int mt = 0; mt < 4; ++mt)
#pragma unroll
            for (int r = 0; r < 4; ++r) {
                float o = (acc1[mt][nt][r] + b1v) * (acc2[mt][nt][r] + b2v);
                OUT[(size_t)(t0 + mt * 16 + quad * 4 + r) * HIDDEN + h * DKV + e] = (_Float16)o;
            }
    }
}

// ---------------------------------------------------------------------------
// Per-chunk S^T[dv][dk] = sum_j V[j][dv] K[j][dk], MFMA.
// ---------------------------------------------------------------------------
__global__ __launch_bounds__(256) void ktv_mfma(const _Float16* __restrict__ Kf,
                                                const _Float16* __restrict__ VT,
                                                float* __restrict__ G)
{
    __shared__ _Float16 kt[128 * 72];
    const int c = blockIdx.x;
    const int bh = blockIdx.y;
    const int b = bh >> 3, h = bh & 7;
    const int tid = threadIdx.x;
    const int w = tid >> 6;
    const int l = tid & 63;
    const int lane16 = l & 15;
    const int quad = l >> 4;
    const size_t rowbase = (size_t)b * T_SEQ + (size_t)c * CHUNK_L;

    {
        const int dk0 = (tid >> 4) * 8;
        const int jb = (tid & 15) * 4;
        half8 r0 = *(const half8*)&Kf[(rowbase + jb + 0) * HIDDEN + h * DKV + dk0];
        half8 r1 = *(const half8*)&Kf[(rowbase + jb + 1) * HIDDEN + h * DKV + dk0];
        half8 r2 = *(const half8*)&Kf[(rowbase + jb + 2) * HIDDEN + h * DKV + dk0];
        half8 r3 = *(const half8*)&Kf[(rowbase + jb + 3) * HIDDEN + h * DKV + dk0];
#pragma unroll
        for (int dk = 0; dk < 8; ++dk) {
            HBits a0, a1, a2, a3;
            a0.h = r0[dk]; a1.h = r1[dk]; a2.h = r2[dk]; a3.h = r3[dk];
            unsigned int lo = ((unsigned int)a1.u << 16) | a0.u;
            unsigned int hi = ((unsigned int)a3.u << 16) | a2.u;
            *(unsigned int*)&kt[(dk0 + dk) * 72 + jb] = lo;
            *(unsigned int*)&kt[(dk0 + dk) * 72 + jb + 2] = hi;
        }
    }
    __syncthreads();

    const int m0 = (w >> 1) * 64;
    const int n0 = (w & 1) * 64;
    floatx4 acc[4][4];
#pragma unroll
    for (int i = 0; i < 4; ++i)
#pragma unroll
        for (int j = 0; j < 4; ++j)
            acc[i][j] = (floatx4){0.f, 0.f, 0.f, 0.f};

#pragma unroll
    for (int s = 0; s < 2; ++s) {
        half8 a[4], bb[4];
#pragma unroll
        for (int mt = 0; mt < 4; ++mt) {
            int dv = m0 + mt * 16 + lane16;
            a[mt] = *(const half8*)&VT[((size_t)bh * DKV + dv) * T_SEQ + c * CHUNK_L + s * 32 + quad * 8];
        }
#pragma unroll
        for (int nt = 0; nt < 4; ++nt)
            bb[nt] = *(const half8*)&kt[(n0 + nt * 16 + lane16) * 72 + s * 32 + quad * 8];
#pragma unroll
        for (int mt = 0; mt < 4; ++mt)
#pragma unroll
            for (int nt = 0; nt < 4; ++nt)
                acc[mt][nt] = __builtin_amdgcn_mfma_f32_16x16x32_f16(a[mt], bb[nt], acc[mt][nt], 0, 0, 0);
    }

    float* Gp = G + ((size_t)bh * NCH + c) * (DKV * DKV);
#pragma unroll
    for (int mt = 0; mt < 4; ++mt)
#pragma unroll
        for (int nt = 0; nt < 4; ++nt)
#pragma unroll
            for (int r = 0; r < 4; ++r)
                Gp[(size_t)(m0 + mt * 16 + quad * 4 + r) * DKV + n0 + nt * 16 + lane16] =
                    acc[mt][nt][r];
}

// ---------------------------------------------------------------------------
// Exclusive prefix over chunks; G fp32 in -> Gh fp16 out (scaled by SCALE_P).
// ---------------------------------------------------------------------------
__global__ void prefix_kernel(const float* __restrict__ G, _Float16* __restrict__ Gh)
{
    int idx = blockIdx.x * 256 + threadIdx.x;   // 16 * 16384
    int bh = idx >> 14;
    int e = idx & 16383;
    const float* p = G + (size_t)bh * NCH * 16384 + e;
    _Float16* q = Gh + (size_t)bh * NCH * 16384 + e;
    float run = 0.f;
#pragma unroll
    for (int c = 0; c < NCH; ++c) {
        q[(size_t)c * 16384] = (_Float16)(run * SCALE_P);
        run += p[(size_t)c * 16384];
    }
}

// ---------------------------------------------------------------------------
// Attention per chunk, MFMA.
// ---------------------------------------------------------------------------
__global__ __launch_bounds__(256) void attn_mfma(const _Float16* __restrict__ Qf,
                                                 const _Float16* __restrict__ Kf,
                                                 const _Float16* __restrict__ VT,
                                                 const _Float16* __restrict__ Gh,
                                                 _Float16* __restrict__ O)
{
    __shared__ _Float16 ps[2 * 64 * 32];
    const int c = blockIdx.x;
    const int bh = blockIdx.y;
    const int b = bh >> 3, h = bh & 7;
    const int tid = threadIdx.x;
    const int w = tid >> 6;
    const int l = tid & 63;
    const int lane16 = l & 15;
    const int quad = l >> 4;
    const size_t rowbase = (size_t)b * T_SEQ + (size_t)c * CHUNK_L;

    {
        const int m0 = (w >> 1) * 32;
        const int n0 = (w & 1) * 32;
        floatx4 aq[2][2];
#pragma unroll
        for (int i = 0; i < 2; ++i)
#pragma unroll
            for (int j = 0; j < 2; ++j)
                aq[i][j] = (floatx4){0.f, 0.f, 0.f, 0.f};
#pragma unroll
        for (int s = 0; s < 4; ++s) {
            half8 a[2], bb[2];
#pragma unroll
            for (int mt = 0; mt < 2; ++mt)
                a[mt] = *(const half8*)&Qf[(rowbase + m0 + mt * 16 + lane16) * HIDDEN +
                                           h * DKV + s * 32 + quad * 8];
#pragma unroll
            for (int nt = 0; nt < 2; ++nt)
                bb[nt] = *(const half8*)&Kf[(rowbase + n0 + nt * 16 + lane16) * HIDDEN +
                                            h * DKV + s * 32 + quad * 8];
#pragma unroll
            for (int mt = 0; mt < 2; ++mt)
#pragma unroll
                for (int nt = 0; nt < 2; ++nt)
                    aq[mt][nt] = __builtin_amdgcn_mfma_f32_16x16x32_f16(a[mt], bb[nt], aq[mt][nt], 0, 0, 0);
        }
#pragma unroll
        for (int mt = 0; mt < 2; ++mt)
#pragma unroll
            for (int nt = 0; nt < 2; ++nt) {
                int j = n0 + nt * 16 + lane16;
#pragma unroll
                for (int r = 0; r < 4; ++r) {
                    int i = m0 + mt * 16 + quad * 4 + r;
                    float v = (j <= i) ? aq[mt][nt][r] * SCALE_P : 0.f;
                    ps[(j >> 5) * 2048 + i * 32 + (j & 31)] = (_Float16)v;
                }
            }
    }
    __syncthreads();

    const int n0o = w * 32;
    floatx4 accO[4][2];
#pragma unroll
    for (int i = 0; i < 4; ++i)
#pragma unroll
        for (int j = 0; j < 2; ++j)
            accO[i][j] = (floatx4){0.f, 0.f, 0.f, 0.f};

#pragma unroll
    for (int s = 0; s < 2; ++s) {
        half8 a[4], bb[2];
#pragma unroll
        for (int mt = 0; mt < 4; ++mt)
            a[mt] = *(const half8*)&ps[s * 2048 + (mt * 16 + lane16) * 32 + quad * 8];
#pragma unroll
        for (int nt = 0; nt < 2; ++nt) {
            int dv = n0o + nt * 16 + lane16;
            bb[nt] = *(const half8*)&VT[((size_t)bh * DKV + dv) * T_SEQ + c * CHUNK_L + s * 32 + quad * 8];
        }
#pragma unroll
        for (int mt = 0; mt < 4; ++mt)
#pragma unroll
            for (int nt = 0; nt < 2; ++nt)
                accO[mt][nt] = __builtin_amdgcn_mfma_f32_16x16x32_f16(a[mt], bb[nt], accO[mt][nt], 0, 0, 0);
    }

    const _Float16* gh = Gh + ((size_t)bh * NCH + c) * (DKV * DKV);
#pragma unroll
    for (int s = 0; s < 4; ++s) {
        half8 a[4], bb[2];
#pragma unroll
        for (int mt = 0; mt < 4; ++mt)
            a[mt] = *(const half8*)&Qf[(rowbase + mt * 16 + lane16) * HIDDEN +
                                       h * DKV + s * 32 + quad * 8];
#pragma unroll
        for (int nt = 0; nt < 2; ++nt) {
            int dv = n0o + nt * 16 + lane16;
            bb[nt] = *(const half8*)&gh[(size_t)dv * DKV + s * 32 + quad * 8];
        }
#pragma unroll
        for (int mt = 0; mt < 4; ++mt)
#pragma unroll
            for (int nt = 0; nt < 2; ++nt)
                accO[mt][nt] = __builtin_amdgcn_mfma_f32_16x16x32_f16(a[mt], bb[nt], accO[mt][nt], 0, 0, 0);
    }

#pragma unroll
    for (int mt = 0; mt < 4; ++mt)
#pragma unroll
        for (int nt = 0; nt < 2; ++nt)
#pragma unroll
            for (int r = 0; r < 4; ++r)
                O[(rowbase + mt * 16 + quad * 4 + r) * HIDDEN + h * DKV + n0o + nt * 16 + lane16] =
                    (_Float16)(accO[mt][nt][r] * OEPS);
}

// ---------------------------------------------------------------------------
extern "C" void kernel_launch(void* const* d_in, const int* in_sizes, int n_in,
                              void* d_out, int out_size, void* d_ws, size_t ws_size,
                              hipStream_t stream)
{
    (void)in_sizes; (void)n_in; (void)out_size; (void)ws_size;
    const float* hs = (const float*)d_in[0];
    const float* wq = (const float*)d_in[1];
    const float* wk = (const float*)d_in[2];
    const float* wv = (const float*)d_in[3];
    const float* wo = (const float*)d_in[4];
    const float* cq = (const float*)d_in[5];
    const float* ck = (const float*)d_in[6];
    const float* cv = (const float*)d_in[7];
    const float* fmq_w1 = (const float*)d_in[8];
    const float* fmq_b1 = (const float*)d_in[9];
    const float* fmq_w2 = (const float*)d_in[10];
    const float* fmq_b2 = (const float*)d_in[11];
    const float* fmk_w1 = (const float*)d_in[12];
    const float* fmk_b1 = (const float*)d_in[13];
    const float* fmk_w2 = (const float*)d_in[14];
    const float* fmk_b2 = (const float*)d_in[15];
    float* out = (float*)d_out;
    char* ws = (char*)d_ws;

    const size_t MB = 1024 * 1024;
    _Float16* h16    = (_Float16*)(ws + 0);          // dead after lin gemms -> qf16
    _Float16* qf16   = (_Float16*)(ws + 0);
    _Float16* wq16   = (_Float16*)(ws + 16 * MB);    // weight block, alive whole run
    _Float16* wk16   = wq16 + (1 << 20);
    _Float16* wv16   = wq16 + (2 << 20);
    _Float16* wo16   = wq16 + (3 << 20);
    _Float16* fmw    = wq16 + (4 << 20);             // 4 x 16384 halfs
    _Float16* qlin16 = (_Float16*)(ws + 32 * MB);    // dead after conv -> kf16
    _Float16* kf16   = (_Float16*)(ws + 32 * MB);
    _Float16* klin16 = (_Float16*)(ws + 48 * MB);    // dead after conv -> O16
    _Float16* O16    = (_Float16*)(ws + 48 * MB);
    _Float16* vlin16 = (_Float16*)(ws + 64 * MB);    // dead after conv-v
    _Float16* Gh     = (_Float16*)(ws + 64 * MB);    // 32 MB
    _Float16* qc16   = (_Float16*)(ws + 80 * MB);    // dead after fm_q
    _Float16* kc16   = (_Float16*)(ws + 96 * MB);    // dead after fm_k
    _Float16* vT     = (_Float16*)(ws + 112 * MB);   // alive till attn
    float*    G      = (float*)(ws + 128 * MB);      // 64 MB fp32

    // ---- casts (3 launches) ----
    cast_f32_f16<<<4096, 256, 0, stream>>>(hs, h16, BT * HIDDEN / 8);
    cast4_f32_f16<<<dim3(512, 4), 256, 0, stream>>>(wq, wk, wv, wo, wq16, wk16, wv16, wo16,
                                                    HIDDEN * HIDDEN / 8);
    cast4_f32_f16<<<dim3(8, 4), 256, 0, stream>>>(fmq_w1, fmq_w2, fmk_w1, fmk_w2,
                                                  fmw, fmw + 16384, fmw + 2 * 16384, fmw + 3 * 16384,
                                                  DKV * DKV / 8);

    // ---- input projections ----
    dim3 gg(HIDDEN / 128, BT / 128);
    gemm_nt_f16_h16<<<gg, 256, 0, stream>>>(h16, wq16, qlin16, BT, HIDDEN, HIDDEN);
    gemm_nt_f16_h16<<<gg, 256, 0, stream>>>(h16, wk16, klin16, BT, HIDDEN, HIDDEN);
    gemm_nt_f16_h16<<<gg, 256, 0, stream>>>(h16, wv16, vlin16, BT, HIDDEN, HIDDEN);

    // ---- conv + silu ----
    conv_silu_col<<<(128 * (BT / CSTRIPE)) / 256, 256, 0, stream>>>(qlin16, cq, qc16);
    conv_silu_col<<<(128 * (BT / CSTRIPE)) / 256, 256, 0, stream>>>(klin16, ck, kc16);
    dim3 cg(T_SEQ / 64, HIDDEN / 64, BATCH);
    conv_silu_T<<<cg, 256, 0, stream>>>(vlin16, cv, vT);

    // ---- feature maps ----
    dim3 fg(BT / 64, NHEAD);
    fm_mfma<<<fg, 256, 0, stream>>>(qc16, fmw, fmq_b1, fmw + 16384, fmq_b2, qf16);
    fm_mfma<<<fg, 256, 0, stream>>>(kc16, fmw + 2 * 16384, fmk_b1, fmw + 3 * 16384, fmk_b2, kf16);

    // ---- chunked linear attention ----
    dim3 ag(NCH, BATCH * NHEAD);
    ktv_mfma<<<ag, 256, 0, stream>>>(kf16, vT, G);
    prefix_kernel<<<(16 * 16384) / 256, 256, 0, stream>>>(G, Gh);
    attn_mfma<<<ag, 256, 0, stream>>>(qf16, kf16, vT, Gh, O16);

    // ---- output projection (undo SCALE_O) ----
    gemm_nt_f16_f32<<<gg, 256, 0, stream>>>(O16, wo16, out, BT, HIDDEN, HIDDEN, 1.0f / SCALE_O);
}

// Round 5
// 351.109 us; speedup vs baseline: 3.7920x; 1.1069x over previous
//
#include <hip/hip_runtime.h>
#include <cstdint>
#include <cstddef>

#define T_SEQ 4096
#define BATCH 2
#define HIDDEN 1024
#define NHEAD 8
#define DKV 128
#define BT (BATCH * T_SEQ)   // 8192
#define NCH 64               // chunks per batch
#define CHUNK_L 64
#define QSCALE 0.08838834764831845f
#define SCALE_P 1024.0f
#define SCALE_O 8192.0f
// combined attn epilogue factor: QSCALE * SCALE_O / SCALE_P
#define OEPS 0.7071067811865476f

typedef _Float16 half8 __attribute__((ext_vector_type(8)));
typedef float floatx4 __attribute__((ext_vector_type(4)));

union HBits { _Float16 h; unsigned short u; };

// ---------------------------------------------------------------------------
// fp32 -> fp16 cast, 8 elements/thread
// ---------------------------------------------------------------------------
__global__ void cast_f32_f16(const float* __restrict__ X, _Float16* __restrict__ Y, int n8)
{
    int idx = blockIdx.x * 256 + threadIdx.x;
    if (idx < n8) {
        float4 a = ((const float4*)X)[idx * 2];
        float4 b = ((const float4*)X)[idx * 2 + 1];
        half8 h = { (_Float16)a.x, (_Float16)a.y, (_Float16)a.z, (_Float16)a.w,
                    (_Float16)b.x, (_Float16)b.y, (_Float16)b.z, (_Float16)b.w };
        *(half8*)&Y[idx * 8] = h;
    }
}

// 4 tensors in one launch; blockIdx.y selects tensor.
__global__ void cast4_f32_f16(const float* __restrict__ A, const float* __restrict__ B,
                              const float* __restrict__ C, const float* __restrict__ D,
                              _Float16* __restrict__ a, _Float16* __restrict__ b,
                              _Float16* __restrict__ c, _Float16* __restrict__ d, int n8)
{
    int sel = blockIdx.y;
    const float* src = (sel == 0) ? A : (sel == 1) ? B : (sel == 2) ? C : D;
    _Float16* dst = (sel == 0) ? a : (sel == 1) ? b : (sel == 2) ? c : d;
    int idx = blockIdx.x * 256 + threadIdx.x;
    if (idx < n8) {
        float4 u = ((const float4*)src)[idx * 2];
        float4 v = ((const float4*)src)[idx * 2 + 1];
        half8 h = { (_Float16)u.x, (_Float16)u.y, (_Float16)u.z, (_Float16)u.w,
                    (_Float16)v.x, (_Float16)v.y, (_Float16)v.z, (_Float16)v.w };
        *(half8*)&dst[idx * 8] = h;
    }
}

// ---------------------------------------------------------------------------
// GEMM (NT) fp16 MFMA, fp16 out: C16[M,N] = A16[M,K] * W16[N,K]^T
// 128x128 tile, BK=32, 4 waves (2x2), 64x64/wave. global_load_lds staging.
// ---------------------------------------------------------------------------
__global__ __launch_bounds__(256) void gemm_nt_f16_h16(const _Float16* __restrict__ A,
                                                       const _Float16* __restrict__ W,
                                                       _Float16* __restrict__ C,
                                                       int M, int N, int K)
{
    __shared__ _Float16 As[128 * 32];
    __shared__ _Float16 Ws[128 * 32];
    const int bm = blockIdx.y * 128;
    const int bn = blockIdx.x * 128;
    const int tid = threadIdx.x;
    const int w = tid >> 6;
    const int l = tid & 63;
    const int wm = (w >> 1) * 64;
    const int wn = (w & 1) * 64;
    const int lane16 = l & 15;
    const int quad = l >> 4;
    const int srow = w * 16 + (l >> 2);
    const int skh = (l & 3) * 8;

    floatx4 acc[4][4];
#pragma unroll
    for (int i = 0; i < 4; ++i)
#pragma unroll
        for (int j = 0; j < 4; ++j)
            acc[i][j] = (floatx4){0.f, 0.f, 0.f, 0.f};

    for (int k0 = 0; k0 < K; k0 += 32) {
#pragma unroll
        for (int c = 0; c < 2; ++c) {
            int row = c * 64 + srow;
            const _Float16* ga = A + (size_t)(bm + row) * K + k0 + skh;
            const _Float16* gw = W + (size_t)(bn + row) * K + k0 + skh;
            __builtin_amdgcn_global_load_lds(
                (const __attribute__((address_space(1))) void*)ga,
                (__attribute__((address_space(3))) void*)(As + c * 2048 + w * 512), 16, 0, 0);
            __builtin_amdgcn_global_load_lds(
                (const __attribute__((address_space(1))) void*)gw,
                (__attribute__((address_space(3))) void*)(Ws + c * 2048 + w * 512), 16, 0, 0);
        }
        __syncthreads();

        half8 a[4], b[4];
#pragma unroll
        for (int i = 0; i < 4; ++i) {
            a[i] = *(const half8*)&As[(wm + i * 16 + lane16) * 32 + quad * 8];
            b[i] = *(const half8*)&Ws[(wn + i * 16 + lane16) * 32 + quad * 8];
        }
#pragma unroll
        for (int i = 0; i < 4; ++i)
#pragma unroll
            for (int j = 0; j < 4; ++j)
                acc[i][j] = __builtin_amdgcn_mfma_f32_16x16x32_f16(a[i], b[j], acc[i][j], 0, 0, 0);
        __syncthreads();
    }
#pragma unroll
    for (int i = 0; i < 4; ++i)
#pragma unroll
        for (int j = 0; j < 4; ++j)
#pragma unroll
            for (int r = 0; r < 4; ++r)
                C[(size_t)(bm + wm + i * 16 + quad * 4 + r) * N + bn + wn + j * 16 + lane16] =
                    (_Float16)acc[i][j][r];
}

// ---------------------------------------------------------------------------
// Same GEMM, fp32 out with scale (final projection; scale undoes SCALE_O).
// ---------------------------------------------------------------------------
__global__ __launch_bounds__(256) void gemm_nt_f16_f32(const _Float16* __restrict__ A,
                                                       const _Float16* __restrict__ W,
                                                       float* __restrict__ C,
                                                       int M, int N, int K, float scale)
{
    __shared__ _Float16 As[128 * 32];
    __shared__ _Float16 Ws[128 * 32];
    const int bm = blockIdx.y * 128;
    const int bn = blockIdx.x * 128;
    const int tid = threadIdx.x;
    const int w = tid >> 6;
    const int l = tid & 63;
    const int wm = (w >> 1) * 64;
    const int wn = (w & 1) * 64;
    const int lane16 = l & 15;
    const int quad = l >> 4;
    const int srow = w * 16 + (l >> 2);
    const int skh = (l & 3) * 8;

    floatx4 acc[4][4];
#pragma unroll
    for (int i = 0; i < 4; ++i)
#pragma unroll
        for (int j = 0; j < 4; ++j)
            acc[i][j] = (floatx4){0.f, 0.f, 0.f, 0.f};

    for (int k0 = 0; k0 < K; k0 += 32) {
#pragma unroll
        for (int c = 0; c < 2; ++c) {
            int row = c * 64 + srow;
            const _Float16* ga = A + (size_t)(bm + row) * K + k0 + skh;
            const _Float16* gw = W + (size_t)(bn + row) * K + k0 + skh;
            __builtin_amdgcn_global_load_lds(
                (const __attribute__((address_space(1))) void*)ga,
                (__attribute__((address_space(3))) void*)(As + c * 2048 + w * 512), 16, 0, 0);
            __builtin_amdgcn_global_load_lds(
                (const __attribute__((address_space(1))) void*)gw,
                (__attribute__((address_space(3))) void*)(Ws + c * 2048 + w * 512), 16, 0, 0);
        }
        __syncthreads();

        half8 a[4], b[4];
#pragma unroll
        for (int i = 0; i < 4; ++i) {
            a[i] = *(const half8*)&As[(wm + i * 16 + lane16) * 32 + quad * 8];
            b[i] = *(const half8*)&Ws[(wn + i * 16 + lane16) * 32 + quad * 8];
        }
#pragma unroll
        for (int i = 0; i < 4; ++i)
#pragma unroll
            for (int j = 0; j < 4; ++j)
                acc[i][j] = __builtin_amdgcn_mfma_f32_16x16x32_f16(a[i], b[j], acc[i][j], 0, 0, 0);
        __syncthreads();
    }
#pragma unroll
    for (int i = 0; i < 4; ++i)
#pragma unroll
        for (int j = 0; j < 4; ++j)
#pragma unroll
            for (int r = 0; r < 4; ++r)
                C[(size_t)(bm + wm + i * 16 + quad * 4 + r) * N + bn + wn + j * 16 + lane16] =
                    acc[i][j][r] * scale;
}

// ---------------------------------------------------------------------------
// Causal depthwise conv (K=4) + SiLU, column-walking, fused q/k:
// blockIdx.y selects (q: col 0, Wq, Yq) vs (k: col 1024, Wk, Yk).
// Input row stride ldx (=3072 for fused qkv buffer), output stride 1024.
// ---------------------------------------------------------------------------
#define CSTRIPE 16
__global__ __launch_bounds__(256) void conv_silu_col2(const _Float16* __restrict__ X, int ldx,
                                                      const float* __restrict__ Wq,
                                                      const float* __restrict__ Wk,
                                                      _Float16* __restrict__ Yq,
                                                      _Float16* __restrict__ Yk)
{
    const int sel = blockIdx.y;
    const _Float16* Xs = X + sel * HIDDEN;
    const float* Wc = sel ? Wk : Wq;
    _Float16* Y = sel ? Yk : Yq;

    int gid = blockIdx.x * 256 + threadIdx.x;     // 128 chunks x (BT/16) stripes
    int c = gid & 127;
    int sg = gid >> 7;
    int r0 = sg * CSTRIPE;
    int tloc = r0 & (T_SEQ - 1);
    int d0 = c * 8;

    float w0[8], w1[8], w2[8], w3[8];
#pragma unroll
    for (int e = 0; e < 8; ++e) {
        float4 wv = *(const float4*)&Wc[(d0 + e) * 4];
        w0[e] = wv.x; w1[e] = wv.y; w2[e] = wv.z; w3[e] = wv.w;
    }

    half8 xm1 = {0,0,0,0,0,0,0,0}, xm2 = xm1, xm3 = xm1;
    if (tloc >= 1) xm1 = *(const half8*)&Xs[(size_t)(r0 - 1) * ldx + d0];
    if (tloc >= 2) xm2 = *(const half8*)&Xs[(size_t)(r0 - 2) * ldx + d0];
    if (tloc >= 3) xm3 = *(const half8*)&Xs[(size_t)(r0 - 3) * ldx + d0];

    for (int i = 0; i < CSTRIPE; ++i) {
        half8 x0 = *(const half8*)&Xs[(size_t)(r0 + i) * ldx + d0];
        half8 o;
#pragma unroll
        for (int e = 0; e < 8; ++e) {
            float acc = fmaf((float)x0[e], w3[e],
                        fmaf((float)xm1[e], w2[e],
                        fmaf((float)xm2[e], w1[e], (float)xm3[e] * w0[e])));
            o[e] = (_Float16)(acc / (1.f + __expf(-acc)));
        }
        *(half8*)&Y[(size_t)(r0 + i) * HIDDEN + d0] = o;
        xm3 = xm2; xm2 = xm1; xm1 = x0;
    }
}

// ---------------------------------------------------------------------------
// Conv + SiLU for V, writing TRANSPOSED: vT[b*1024 + d][t]  (fp16).
// X row stride ldx, column offset applied by caller via pointer.
// ---------------------------------------------------------------------------
__global__ __launch_bounds__(256) void conv_silu_T(const _Float16* __restrict__ X, int ldx,
                                                   const float* __restrict__ Wc,
                                                   _Float16* __restrict__ VT)
{
    __shared__ _Float16 xs[67 * 64];
    const int t0 = blockIdx.x * 64;
    const int dt = blockIdx.y * 64;
    const int z = blockIdx.z;
    const int tid = threadIdx.x;

#pragma unroll
    for (int i = 0; i < 3; ++i) {
        int p = tid + 256 * i;
        if (p < 536) {
            int row = p >> 3, d8 = (p & 7) * 8;
            int t = t0 - 3 + row;
            half8 v;
            if (t >= 0)
                v = *(const half8*)&X[((size_t)z * T_SEQ + t) * ldx + dt + d8];
            else
                v = (half8){0, 0, 0, 0, 0, 0, 0, 0};
            *(half8*)&xs[row * 64 + d8] = v;
        }
    }
    __syncthreads();

    const int d = tid & 63;
    const int dg = dt + d;
    float4 w = *(const float4*)&Wc[dg * 4];
#pragma unroll
    for (int u = 0; u < 2; ++u) {
        int tg = (tid >> 6) + u * 4;
        half8 o;
#pragma unroll
        for (int s = 0; s < 8; ++s) {
            int base = (tg * 8 + s + 3) * 64 + d;
            float acc = (float)xs[base] * w.w
                      + (float)xs[base - 64] * w.z
                      + (float)xs[base - 128] * w.y
                      + (float)xs[base - 192] * w.x;
            o[s] = (_Float16)(acc / (1.f + __expf(-acc)));
        }
        *(half8*)&VT[((size_t)z * HIDDEN + dg) * T_SEQ + t0 + tg * 8] = o;
    }
}

// ---------------------------------------------------------------------------
// Feature map, MFMA, fused q/k via blockIdx.z.
// ---------------------------------------------------------------------------
__global__ __launch_bounds__(256) void fm_mfma2(const _Float16* __restrict__ Xq,
                                                const _Float16* __restrict__ Xk,
                                                const _Float16* __restrict__ Wfm,  // 4x16384
                                                const float* __restrict__ Bq1,
                                                const float* __restrict__ Bq2,
                                                const float* __restrict__ Bk1,
                                                const float* __restrict__ Bk2,
                                                _Float16* __restrict__ OUTq,
                                                _Float16* __restrict__ OUTk)
{
    const int sel = blockIdx.z;
    const _Float16* X = sel ? Xk : Xq;
    const _Float16* W1h = Wfm + (sel ? 2 * 16384 : 0);
    const _Float16* W2h = Wfm + (sel ? 3 * 16384 : 16384);
    const float* B1 = sel ? Bk1 : Bq1;
    const float* B2 = sel ? Bk2 : Bq2;
    _Float16* OUT = sel ? OUTk : OUTq;

    __shared__ _Float16 xs[4 * 64 * 32];   // [kstep][row][32]
    const int t0 = blockIdx.x * 64;
    const int h = blockIdx.y;
    const int tid = threadIdx.x;
    const int w = tid >> 6;
    const int l = tid & 63;
    const int lane16 = l & 15;
    const int quad = l >> 4;

#pragma unroll
    for (int c = 0; c < 4; ++c) {
        int row = c * 16 + (l >> 2);
        const _Float16* g = X + (size_t)(t0 + row) * HIDDEN + h * DKV + w * 32 + (l & 3) * 8;
        __builtin_amdgcn_global_load_lds(
            (const __attribute__((address_space(1))) void*)g,
            (__attribute__((address_space(3))) void*)(xs + w * 2048 + c * 512), 16, 0, 0);
    }
    __syncthreads();

    floatx4 acc1[4][2], acc2[4][2];
#pragma unroll
    for (int i = 0; i < 4; ++i)
#pragma unroll
        for (int j = 0; j < 2; ++j) {
            acc1[i][j] = (floatx4){0.f, 0.f, 0.f, 0.f};
            acc2[i][j] = (floatx4){0.f, 0.f, 0.f, 0.f};
        }

#pragma unroll
    for (int s = 0; s < 4; ++s) {
        half8 a[4];
#pragma unroll
        for (int mt = 0; mt < 4; ++mt)
            a[mt] = *(const half8*)&xs[s * 2048 + (mt * 16 + lane16) * 32 + quad * 8];
#pragma unroll
        for (int nt = 0; nt < 2; ++nt) {
            int e = w * 32 + nt * 16 + lane16;
            half8 b1 = *(const half8*)&W1h[(size_t)e * DKV + s * 32 + quad * 8];
            half8 b2 = *(const half8*)&W2h[(size_t)e * DKV + s * 32 + quad * 8];
#pragma unroll
            for (int mt = 0; mt < 4; ++mt) {
                acc1[mt][nt] = __builtin_amdgcn_mfma_f32_16x16x32_f16(a[mt], b1, acc1[mt][nt], 0, 0, 0);
                acc2[mt][nt] = __builtin_amdgcn_mfma_f32_16x16x32_f16(a[mt], b2, acc2[mt][nt], 0, 0, 0);
            }
        }
    }

#pragma unroll
    for (int nt = 0; nt < 2; ++nt) {
        int e = w * 32 + nt * 16 + lane16;
        float b1v = B1[e], b2v = B2[e];
#pragma unroll
        for (int mt = 0; mt < 4; ++mt)
#pragma unroll
            for (int r = 0; r < 4; ++r) {
                float o = (acc1[mt][nt][r] + b1v) * (acc2[mt][nt][r] + b2v);
                OUT[(size_t)(t0 + mt * 16 + quad * 4 + r) * HIDDEN + h * DKV + e] = (_Float16)o;
            }
    }
}

// ---------------------------------------------------------------------------
// Per-chunk S^T[dv][dk] = sum_j V[j][dv] K[j][dk], MFMA.
// ---------------------------------------------------------------------------
__global__ __launch_bounds__(256) void ktv_mfma(const _Float16* __restrict__ Kf,
                                                const _Float16* __restrict__ VT,
                                                float* __restrict__ G)
{
    __shared__ _Float16 kt[128 * 72];
    const int c = blockIdx.x;
    const int bh = blockIdx.y;
    const int b = bh >> 3, h = bh & 7;
    const int tid = threadIdx.x;
    const int w = tid >> 6;
    const int l = tid & 63;
    const int lane16 = l & 15;
    const int quad = l >> 4;
    const size_t rowbase = (size_t)b * T_SEQ + (size_t)c * CHUNK_L;

    {
        const int dk0 = (tid >> 4) * 8;
        const int jb = (tid & 15) * 4;
        half8 r0 = *(const half8*)&Kf[(rowbase + jb + 0) * HIDDEN + h * DKV + dk0];
        half8 r1 = *(const half8*)&Kf[(rowbase + jb + 1) * HIDDEN + h * DKV + dk0];
        half8 r2 = *(const half8*)&Kf[(rowbase + jb + 2) * HIDDEN + h * DKV + dk0];
        half8 r3 = *(const half8*)&Kf[(rowbase + jb + 3) * HIDDEN + h * DKV + dk0];
#pragma unroll
        for (int dk = 0; dk < 8; ++dk) {
            HBits a0, a1, a2, a3;
            a0.h = r0[dk]; a1.h = r1[dk]; a2.h = r2[dk]; a3.h = r3[dk];
            unsigned int lo = ((unsigned int)a1.u << 16) | a0.u;
            unsigned int hi = ((unsigned int)a3.u << 16) | a2.u;
            *(unsigned int*)&kt[(dk0 + dk) * 72 + jb] = lo;
            *(unsigned int*)&kt[(dk0 + dk) * 72 + jb + 2] = hi;
        }
    }
    __syncthreads();

    const int m0 = (w >> 1) * 64;
    const int n0 = (w & 1) * 64;
    floatx4 acc[4][4];
#pragma unroll
    for (int i = 0; i < 4; ++i)
#pragma unroll
        for (int j = 0; j < 4; ++j)
            acc[i][j] = (floatx4){0.f, 0.f, 0.f, 0.f};

#pragma unroll
    for (int s = 0; s < 2; ++s) {
        half8 a[4], bb[4];
#pragma unroll
        for (int mt = 0; mt < 4; ++mt) {
            int dv = m0 + mt * 16 + lane16;
            a[mt] = *(const half8*)&VT[((size_t)bh * DKV + dv) * T_SEQ + c * CHUNK_L + s * 32 + quad * 8];
        }
#pragma unroll
        for (int nt = 0; nt < 4; ++nt)
            bb[nt] = *(const half8*)&kt[(n0 + nt * 16 + lane16) * 72 + s * 32 + quad * 8];
#pragma unroll
        for (int mt = 0; mt < 4; ++mt)
#pragma unroll
            for (int nt = 0; nt < 4; ++nt)
                acc[mt][nt] = __builtin_amdgcn_mfma_f32_16x16x32_f16(a[mt], bb[nt], acc[mt][nt], 0, 0, 0);
    }

    float* Gp = G + ((size_t)bh * NCH + c) * (DKV * DKV);
#pragma unroll
    for (int mt = 0; mt < 4; ++mt)
#pragma unroll
        for (int nt = 0; nt < 4; ++nt)
#pragma unroll
            for (int r = 0; r < 4; ++r)
                Gp[(size_t)(m0 + mt * 16 + quad * 4 + r) * DKV + n0 + nt * 16 + lane16] =
                    acc[mt][nt][r];
}

// ---------------------------------------------------------------------------
// Exclusive prefix over chunks; G fp32 in -> Gh fp16 out (scaled by SCALE_P).
// ---------------------------------------------------------------------------
__global__ void prefix_kernel(const float* __restrict__ G, _Float16* __restrict__ Gh)
{
    int idx = blockIdx.x * 256 + threadIdx.x;   // 16 * 16384
    int bh = idx >> 14;
    int e = idx & 16383;
    const float* p = G + (size_t)bh * NCH * 16384 + e;
    _Float16* q = Gh + (size_t)bh * NCH * 16384 + e;
    float run = 0.f;
#pragma unroll
    for (int c = 0; c < NCH; ++c) {
        q[(size_t)c * 16384] = (_Float16)(run * SCALE_P);
        run += p[(size_t)c * 16384];
    }
}

// ---------------------------------------------------------------------------
// Attention per chunk, MFMA.
// ---------------------------------------------------------------------------
__global__ __launch_bounds__(256) void attn_mfma(const _Float16* __restrict__ Qf,
                                                 const _Float16* __restrict__ Kf,
                                                 const _Float16* __restrict__ VT,
                                                 const _Float16* __restrict__ Gh,
                                                 _Float16* __restrict__ O)
{
    __shared__ _Float16 ps[2 * 64 * 32];
    const int c = blockIdx.x;
    const int bh = blockIdx.y;
    const int b = bh >> 3, h = bh & 7;
    const int tid = threadIdx.x;
    const int w = tid >> 6;
    const int l = tid & 63;
    const int lane16 = l & 15;
    const int quad = l >> 4;
    const size_t rowbase = (size_t)b * T_SEQ + (size_t)c * CHUNK_L;

    {
        const int m0 = (w >> 1) * 32;
        const int n0 = (w & 1) * 32;
        floatx4 aq[2][2];
#pragma unroll
        for (int i = 0; i < 2; ++i)
#pragma unroll
            for (int j = 0; j < 2; ++j)
                aq[i][j] = (floatx4){0.f, 0.f, 0.f, 0.f};
#pragma unroll
        for (int s = 0; s < 4; ++s) {
            half8 a[2], bb[2];
#pragma unroll
            for (int mt = 0; mt < 2; ++mt)
                a[mt] = *(const half8*)&Qf[(rowbase + m0 + mt * 16 + lane16) * HIDDEN +
                                           h * DKV + s * 32 + quad * 8];
#pragma unroll
            for (int nt = 0; nt < 2; ++nt)
                bb[nt] = *(const half8*)&Kf[(rowbase + n0 + nt * 16 + lane16) * HIDDEN +
                                            h * DKV + s * 32 + quad * 8];
#pragma unroll
            for (int mt = 0; mt < 2; ++mt)
#pragma unroll
                for (int nt = 0; nt < 2; ++nt)
                    aq[mt][nt] = __builtin_amdgcn_mfma_f32_16x16x32_f16(a[mt], bb[nt], aq[mt][nt], 0, 0, 0);
        }
#pragma unroll
        for (int mt = 0; mt < 2; ++mt)
#pragma unroll
            for (int nt = 0; nt < 2; ++nt) {
                int j = n0 + nt * 16 + lane16;
#pragma unroll
                for (int r = 0; r < 4; ++r) {
                    int i = m0 + mt * 16 + quad * 4 + r;
                    float v = (j <= i) ? aq[mt][nt][r] * SCALE_P : 0.f;
                    ps[(j >> 5) * 2048 + i * 32 + (j & 31)] = (_Float16)v;
                }
            }
    }
    __syncthreads();

    const int n0o = w * 32;
    floatx4 accO[4][2];
#pragma unroll
    for (int i = 0; i < 4; ++i)
#pragma unroll
        for (int j = 0; j < 2; ++j)
            accO[i][j] = (floatx4){0.f, 0.f, 0.f, 0.f};

#pragma unroll
    for (int s = 0; s < 2; ++s) {
        half8 a[4], bb[2];
#pragma unroll
        for (int mt = 0; mt < 4; ++mt)
            a[mt] = *(const half8*)&ps[s * 2048 + (mt * 16 + lane16) * 32 + quad * 8];
#pragma unroll
        for (int nt = 0; nt < 2; ++nt) {
            int dv = n0o + nt * 16 + lane16;
            bb[nt] = *(const half8*)&VT[((size_t)bh * DKV + dv) * T_SEQ + c * CHUNK_L + s * 32 + quad * 8];
        }
#pragma unroll
        for (int mt = 0; mt < 4; ++mt)
#pragma unroll
            for (int nt = 0; nt < 2; ++nt)
                accO[mt][nt] = __builtin_amdgcn_mfma_f32_16x16x32_f16(a[mt], bb[nt], accO[mt][nt], 0, 0, 0);
    }

    const _Float16* gh = Gh + ((size_t)bh * NCH + c) * (DKV * DKV);
#pragma unroll
    for (int s = 0; s < 4; ++s) {
        half8 a[4], bb[2];
#pragma unroll
        for (int mt = 0; mt < 4; ++mt)
            a[mt] = *(const half8*)&Qf[(rowbase + mt * 16 + lane16) * HIDDEN +
                                       h * DKV + s * 32 + quad * 8];
#pragma unroll
        for (int nt = 0; nt < 2; ++nt) {
            int dv = n0o + nt * 16 + lane16;
            bb[nt] = *(const half8*)&gh[(size_t)dv * DKV + s * 32 + quad * 8];
        }
#pragma unroll
        for (int mt = 0; mt < 4; ++mt)
#pragma unroll
            for (int nt = 0; nt < 2; ++nt)
                accO[mt][nt] = __builtin_amdgcn_mfma_f32_16x16x32_f16(a[mt], bb[nt], accO[mt][nt], 0, 0, 0);
    }

#pragma unroll
    for (int mt = 0; mt < 4; ++mt)
#pragma unroll
        for (int nt = 0; nt < 2; ++nt)
#pragma unroll
            for (int r = 0; r < 4; ++r)
                O[(rowbase + mt * 16 + quad * 4 + r) * HIDDEN + h * DKV + n0o + nt * 16 + lane16] =
                    (_Float16)(accO[mt][nt][r] * OEPS);
}

// ---------------------------------------------------------------------------
// Workspace map (192 MiB, phase-aliased):
//   [0,16)    h16 (P0-P1)
//   [16,32)   weights: wq|wk|wv (6MB contiguous N=3072), wo (2MB), fmw (128KB)
//   [32,80)   qkvlin 48MB (P1-P2);  then qf16 [32,48) kf16 [48,64) (P3-P6),
//             Gh [64,96) (P5-P6)
//   [80,96)   qc16 (P2-P3)   (tail of Gh after P3 — ok, Gh written P5)
//   [96,112)  kc16 (P2-P3);  then O16 (P6-P7)
//   [112,128) vT (P2-P6)
//   [128,192) G fp32 (P4-P5)
// ---------------------------------------------------------------------------
extern "C" void kernel_launch(void* const* d_in, const int* in_sizes, int n_in,
                              void* d_out, int out_size, void* d_ws, size_t ws_size,
                              hipStream_t stream)
{
    (void)in_sizes; (void)n_in; (void)out_size; (void)ws_size;
    const float* hs = (const float*)d_in[0];
    const float* wq = (const float*)d_in[1];
    const float* wk = (const float*)d_in[2];
    const float* wv = (const float*)d_in[3];
    const float* wo = (const float*)d_in[4];
    const float* cq = (const float*)d_in[5];
    const float* ck = (const float*)d_in[6];
    const float* cv = (const float*)d_in[7];
    const float* fmq_w1 = (const float*)d_in[8];
    const float* fmq_b1 = (const float*)d_in[9];
    const float* fmq_w2 = (const float*)d_in[10];
    const float* fmq_b2 = (const float*)d_in[11];
    const float* fmk_w1 = (const float*)d_in[12];
    const float* fmk_b1 = (const float*)d_in[13];
    const float* fmk_w2 = (const float*)d_in[14];
    const float* fmk_b2 = (const float*)d_in[15];
    float* out = (float*)d_out;
    char* ws = (char*)d_ws;

    const size_t MB = 1024 * 1024;
    _Float16* h16     = (_Float16*)(ws + 0);
    _Float16* wqkv16  = (_Float16*)(ws + 16 * MB);         // 3072x1024
    _Float16* wo16    = wqkv16 + (3 << 20);
    _Float16* fmw     = wqkv16 + (4 << 20);                // 4 x 16384
    _Float16* qkvlin  = (_Float16*)(ws + 32 * MB);         // [8192][3072]
    _Float16* qf16    = (_Float16*)(ws + 32 * MB);
    _Float16* kf16    = (_Float16*)(ws + 48 * MB);
    _Float16* Gh      = (_Float16*)(ws + 64 * MB);         // 32 MB
    _Float16* qc16    = (_Float16*)(ws + 80 * MB);
    _Float16* kc16    = (_Float16*)(ws + 96 * MB);
    _Float16* O16     = (_Float16*)(ws + 96 * MB);
    _Float16* vT      = (_Float16*)(ws + 112 * MB);
    float*    G       = (float*)(ws + 128 * MB);           // 64 MB

    // ---- P0: casts ----
    cast_f32_f16<<<4096, 256, 0, stream>>>(hs, h16, BT * HIDDEN / 8);
    cast4_f32_f16<<<dim3(512, 4), 256, 0, stream>>>(wq, wk, wv, wo,
                                                    wqkv16, wqkv16 + (1 << 20), wqkv16 + (2 << 20), wo16,
                                                    HIDDEN * HIDDEN / 8);
    cast4_f32_f16<<<dim3(8, 4), 256, 0, stream>>>(fmq_w1, fmq_w2, fmk_w1, fmk_w2,
                                                  fmw, fmw + 16384, fmw + 2 * 16384, fmw + 3 * 16384,
                                                  DKV * DKV / 8);

    // ---- P1: fused QKV projection (N = 3072) ----
    dim3 gqkv(3 * HIDDEN / 128, BT / 128);   // (24, 64) = 1536 blocks
    gemm_nt_f16_h16<<<gqkv, 256, 0, stream>>>(h16, wqkv16, qkvlin, BT, 3 * HIDDEN, HIDDEN);

    // ---- P2: conv + silu (q,k fused; v transposed) ----
    conv_silu_col2<<<dim3((128 * (BT / CSTRIPE)) / 256, 2), 256, 0, stream>>>(
        qkvlin, 3 * HIDDEN, cq, ck, qc16, kc16);
    dim3 cg(T_SEQ / 64, HIDDEN / 64, BATCH);
    conv_silu_T<<<cg, 256, 0, stream>>>(qkvlin + 2 * HIDDEN, 3 * HIDDEN, cv, vT);

    // ---- P3: feature maps (q,k fused) ----
    dim3 fg(BT / 64, NHEAD, 2);
    fm_mfma2<<<fg, 256, 0, stream>>>(qc16, kc16, fmw, fmq_b1, fmq_b2, fmk_b1, fmk_b2, qf16, kf16);

    // ---- P4-P6: chunked linear attention ----
    dim3 ag(NCH, BATCH * NHEAD);
    ktv_mfma<<<ag, 256, 0, stream>>>(kf16, vT, G);
    prefix_kernel<<<(16 * 16384) / 256, 256, 0, stream>>>(G, Gh);
    attn_mfma<<<ag, 256, 0, stream>>>(qf16, kf16, vT, Gh, O16);

    // ---- P7: output projection (undo SCALE_O) ----
    dim3 gg(HIDDEN / 128, BT / 128);
    gemm_nt_f16_f32<<<gg, 256, 0, stream>>>(O16, wo16, out, BT, HIDDEN, HIDDEN, 1.0f / SCALE_O);
}

// Round 6
// 348.233 us; speedup vs baseline: 3.8234x; 1.0083x over previous
//
#include <hip/hip_runtime.h>
#include <cstdint>
#include <cstddef>

#define T_SEQ 4096
#define BATCH 2
#define HIDDEN 1024
#define NHEAD 8
#define DKV 128
#define BT (BATCH * T_SEQ)   // 8192
#define NCH 64               // chunks per batch
#define CHUNK_L 64
#define QSCALE 0.08838834764831845f
#define SCALE_P 1024.0f
#define SCALE_O 8192.0f
// combined attn epilogue factor: QSCALE * SCALE_O / SCALE_P
#define OEPS 0.7071067811865476f

typedef _Float16 half8 __attribute__((ext_vector_type(8)));
typedef float floatx4 __attribute__((ext_vector_type(4)));

union HBits { _Float16 h; unsigned short u; };

// ---------------------------------------------------------------------------
// fp32 -> fp16 cast, 8 elements/thread
// ---------------------------------------------------------------------------
__global__ void cast_f32_f16(const float* __restrict__ X, _Float16* __restrict__ Y, int n8)
{
    int idx = blockIdx.x * 256 + threadIdx.x;
    if (idx < n8) {
        float4 a = ((const float4*)X)[idx * 2];
        float4 b = ((const float4*)X)[idx * 2 + 1];
        half8 h = { (_Float16)a.x, (_Float16)a.y, (_Float16)a.z, (_Float16)a.w,
                    (_Float16)b.x, (_Float16)b.y, (_Float16)b.z, (_Float16)b.w };
        *(half8*)&Y[idx * 8] = h;
    }
}

// 4 tensors in one launch; blockIdx.y selects tensor.
__global__ void cast4_f32_f16(const float* __restrict__ A, const float* __restrict__ B,
                              const float* __restrict__ C, const float* __restrict__ D,
                              _Float16* __restrict__ a, _Float16* __restrict__ b,
                              _Float16* __restrict__ c, _Float16* __restrict__ d, int n8)
{
    int sel = blockIdx.y;
    const float* src = (sel == 0) ? A : (sel == 1) ? B : (sel == 2) ? C : D;
    _Float16* dst = (sel == 0) ? a : (sel == 1) ? b : (sel == 2) ? c : d;
    int idx = blockIdx.x * 256 + threadIdx.x;
    if (idx < n8) {
        float4 u = ((const float4*)src)[idx * 2];
        float4 v = ((const float4*)src)[idx * 2 + 1];
        half8 h = { (_Float16)u.x, (_Float16)u.y, (_Float16)u.z, (_Float16)u.w,
                    (_Float16)v.x, (_Float16)v.y, (_Float16)v.z, (_Float16)v.w };
        *(half8*)&dst[idx * 8] = h;
    }
}

// ---------------------------------------------------------------------------
// GEMM (NT) fp16 MFMA, fp16 out: C16[M,N] = A16[M,K] * W16[N,K]^T
// 128x128 tile, BK=32, 4 waves (2x2), 64x64/wave. global_load_lds staging.
// XOR bank swizzle: logical (row,qc) stored at physical qc^(row&3); staging
// lane loads swizzled global column, reads XOR the quad column.
// ---------------------------------------------------------------------------
__global__ __launch_bounds__(256) void gemm_nt_f16_h16(const _Float16* __restrict__ A,
                                                       const _Float16* __restrict__ W,
                                                       _Float16* __restrict__ C,
                                                       int M, int N, int K)
{
    __shared__ _Float16 As[128 * 32];
    __shared__ _Float16 Ws[128 * 32];
    const int bm = blockIdx.y * 128;
    const int bn = blockIdx.x * 128;
    const int tid = threadIdx.x;
    const int w = tid >> 6;
    const int l = tid & 63;
    const int wm = (w >> 1) * 64;
    const int wn = (w & 1) * 64;
    const int lane16 = l & 15;
    const int quad = l >> 4;
    const int srow = w * 16 + (l >> 2);
    const int skh = (((l & 3) ^ ((l >> 2) & 3)) * 8);   // swizzled source column
    const int rq8 = (quad ^ (lane16 & 3)) * 8;          // swizzled read column

    floatx4 acc[4][4];
#pragma unroll
    for (int i = 0; i < 4; ++i)
#pragma unroll
        for (int j = 0; j < 4; ++j)
            acc[i][j] = (floatx4){0.f, 0.f, 0.f, 0.f};

    for (int k0 = 0; k0 < K; k0 += 32) {
#pragma unroll
        for (int c = 0; c < 2; ++c) {
            int row = c * 64 + srow;
            const _Float16* ga = A + (size_t)(bm + row) * K + k0 + skh;
            const _Float16* gw = W + (size_t)(bn + row) * K + k0 + skh;
            __builtin_amdgcn_global_load_lds(
                (const __attribute__((address_space(1))) void*)ga,
                (__attribute__((address_space(3))) void*)(As + c * 2048 + w * 512), 16, 0, 0);
            __builtin_amdgcn_global_load_lds(
                (const __attribute__((address_space(1))) void*)gw,
                (__attribute__((address_space(3))) void*)(Ws + c * 2048 + w * 512), 16, 0, 0);
        }
        __syncthreads();

        half8 a[4], b[4];
#pragma unroll
        for (int i = 0; i < 4; ++i) {
            a[i] = *(const half8*)&As[(wm + i * 16 + lane16) * 32 + rq8];
            b[i] = *(const half8*)&Ws[(wn + i * 16 + lane16) * 32 + rq8];
        }
#pragma unroll
        for (int i = 0; i < 4; ++i)
#pragma unroll
            for (int j = 0; j < 4; ++j)
                acc[i][j] = __builtin_amdgcn_mfma_f32_16x16x32_f16(a[i], b[j], acc[i][j], 0, 0, 0);
        __syncthreads();
    }
#pragma unroll
    for (int i = 0; i < 4; ++i)
#pragma unroll
        for (int j = 0; j < 4; ++j)
#pragma unroll
            for (int r = 0; r < 4; ++r)
                C[(size_t)(bm + wm + i * 16 + quad * 4 + r) * N + bn + wn + j * 16 + lane16] =
                    (_Float16)acc[i][j][r];
}

// ---------------------------------------------------------------------------
// Same GEMM, fp32 out with scale (final projection; scale undoes SCALE_O).
// ---------------------------------------------------------------------------
__global__ __launch_bounds__(256) void gemm_nt_f16_f32(const _Float16* __restrict__ A,
                                                       const _Float16* __restrict__ W,
                                                       float* __restrict__ C,
                                                       int M, int N, int K, float scale)
{
    __shared__ _Float16 As[128 * 32];
    __shared__ _Float16 Ws[128 * 32];
    const int bm = blockIdx.y * 128;
    const int bn = blockIdx.x * 128;
    const int tid = threadIdx.x;
    const int w = tid >> 6;
    const int l = tid & 63;
    const int wm = (w >> 1) * 64;
    const int wn = (w & 1) * 64;
    const int lane16 = l & 15;
    const int quad = l >> 4;
    const int srow = w * 16 + (l >> 2);
    const int skh = (((l & 3) ^ ((l >> 2) & 3)) * 8);
    const int rq8 = (quad ^ (lane16 & 3)) * 8;

    floatx4 acc[4][4];
#pragma unroll
    for (int i = 0; i < 4; ++i)
#pragma unroll
        for (int j = 0; j < 4; ++j)
            acc[i][j] = (floatx4){0.f, 0.f, 0.f, 0.f};

    for (int k0 = 0; k0 < K; k0 += 32) {
#pragma unroll
        for (int c = 0; c < 2; ++c) {
            int row = c * 64 + srow;
            const _Float16* ga = A + (size_t)(bm + row) * K + k0 + skh;
            const _Float16* gw = W + (size_t)(bn + row) * K + k0 + skh;
            __builtin_amdgcn_global_load_lds(
                (const __attribute__((address_space(1))) void*)ga,
                (__attribute__((address_space(3))) void*)(As + c * 2048 + w * 512), 16, 0, 0);
            __builtin_amdgcn_global_load_lds(
                (const __attribute__((address_space(1))) void*)gw,
                (__attribute__((address_space(3))) void*)(Ws + c * 2048 + w * 512), 16, 0, 0);
        }
        __syncthreads();

        half8 a[4], b[4];
#pragma unroll
        for (int i = 0; i < 4; ++i) {
            a[i] = *(const half8*)&As[(wm + i * 16 + lane16) * 32 + rq8];
            b[i] = *(const half8*)&Ws[(wn + i * 16 + lane16) * 32 + rq8];
        }
#pragma unroll
        for (int i = 0; i < 4; ++i)
#pragma unroll
            for (int j = 0; j < 4; ++j)
                acc[i][j] = __builtin_amdgcn_mfma_f32_16x16x32_f16(a[i], b[j], acc[i][j], 0, 0, 0);
        __syncthreads();
    }
#pragma unroll
    for (int i = 0; i < 4; ++i)
#pragma unroll
        for (int j = 0; j < 4; ++j)
#pragma unroll
            for (int r = 0; r < 4; ++r)
                C[(size_t)(bm + wm + i * 16 + quad * 4 + r) * N + bn + wn + j * 16 + lane16] =
                    acc[i][j][r] * scale;
}

// ---------------------------------------------------------------------------
// Causal depthwise conv (K=4) + SiLU, column-walking, fused q/k.
// ---------------------------------------------------------------------------
#define CSTRIPE 16
__global__ __launch_bounds__(256) void conv_silu_col2(const _Float16* __restrict__ X, int ldx,
                                                      const float* __restrict__ Wq,
                                                      const float* __restrict__ Wk,
                                                      _Float16* __restrict__ Yq,
                                                      _Float16* __restrict__ Yk)
{
    const int sel = blockIdx.y;
    const _Float16* Xs = X + sel * HIDDEN;
    const float* Wc = sel ? Wk : Wq;
    _Float16* Y = sel ? Yk : Yq;

    int gid = blockIdx.x * 256 + threadIdx.x;
    int c = gid & 127;
    int sg = gid >> 7;
    int r0 = sg * CSTRIPE;
    int tloc = r0 & (T_SEQ - 1);
    int d0 = c * 8;

    float w0[8], w1[8], w2[8], w3[8];
#pragma unroll
    for (int e = 0; e < 8; ++e) {
        float4 wv = *(const float4*)&Wc[(d0 + e) * 4];
        w0[e] = wv.x; w1[e] = wv.y; w2[e] = wv.z; w3[e] = wv.w;
    }

    half8 xm1 = {0,0,0,0,0,0,0,0}, xm2 = xm1, xm3 = xm1;
    if (tloc >= 1) xm1 = *(const half8*)&Xs[(size_t)(r0 - 1) * ldx + d0];
    if (tloc >= 2) xm2 = *(const half8*)&Xs[(size_t)(r0 - 2) * ldx + d0];
    if (tloc >= 3) xm3 = *(const half8*)&Xs[(size_t)(r0 - 3) * ldx + d0];

    for (int i = 0; i < CSTRIPE; ++i) {
        half8 x0 = *(const half8*)&Xs[(size_t)(r0 + i) * ldx + d0];
        half8 o;
#pragma unroll
        for (int e = 0; e < 8; ++e) {
            float acc = fmaf((float)x0[e], w3[e],
                        fmaf((float)xm1[e], w2[e],
                        fmaf((float)xm2[e], w1[e], (float)xm3[e] * w0[e])));
            o[e] = (_Float16)(acc / (1.f + __expf(-acc)));
        }
        *(half8*)&Y[(size_t)(r0 + i) * HIDDEN + d0] = o;
        xm3 = xm2; xm2 = xm1; xm1 = x0;
    }
}

// ---------------------------------------------------------------------------
// Conv + SiLU for V, writing TRANSPOSED: vT[b*1024 + d][t]  (fp16).
// ---------------------------------------------------------------------------
__global__ __launch_bounds__(256) void conv_silu_T(const _Float16* __restrict__ X, int ldx,
                                                   const float* __restrict__ Wc,
                                                   _Float16* __restrict__ VT)
{
    __shared__ _Float16 xs[67 * 64];
    const int t0 = blockIdx.x * 64;
    const int dt = blockIdx.y * 64;
    const int z = blockIdx.z;
    const int tid = threadIdx.x;

#pragma unroll
    for (int i = 0; i < 3; ++i) {
        int p = tid + 256 * i;
        if (p < 536) {
            int row = p >> 3, d8 = (p & 7) * 8;
            int t = t0 - 3 + row;
            half8 v;
            if (t >= 0)
                v = *(const half8*)&X[((size_t)z * T_SEQ + t) * ldx + dt + d8];
            else
                v = (half8){0, 0, 0, 0, 0, 0, 0, 0};
            *(half8*)&xs[row * 64 + d8] = v;
        }
    }
    __syncthreads();

    const int d = tid & 63;
    const int dg = dt + d;
    float4 w = *(const float4*)&Wc[dg * 4];
#pragma unroll
    for (int u = 0; u < 2; ++u) {
        int tg = (tid >> 6) + u * 4;
        half8 o;
#pragma unroll
        for (int s = 0; s < 8; ++s) {
            int base = (tg * 8 + s + 3) * 64 + d;
            float acc = (float)xs[base] * w.w
                      + (float)xs[base - 64] * w.z
                      + (float)xs[base - 128] * w.y
                      + (float)xs[base - 192] * w.x;
            o[s] = (_Float16)(acc / (1.f + __expf(-acc)));
        }
        *(half8*)&VT[((size_t)z * HIDDEN + dg) * T_SEQ + t0 + tg * 8] = o;
    }
}

// ---------------------------------------------------------------------------
// Feature map, MFMA, fused q/k via blockIdx.z. Same XOR swizzle on xs.
// ---------------------------------------------------------------------------
__global__ __launch_bounds__(256) void fm_mfma2(const _Float16* __restrict__ Xq,
                                                const _Float16* __restrict__ Xk,
                                                const _Float16* __restrict__ Wfm,  // 4x16384
                                                const float* __restrict__ Bq1,
                                                const float* __restrict__ Bq2,
                                                const float* __restrict__ Bk1,
                                                const float* __restrict__ Bk2,
                                                _Float16* __restrict__ OUTq,
                                                _Float16* __restrict__ OUTk)
{
    const int sel = blockIdx.z;
    const _Float16* X = sel ? Xk : Xq;
    const _Float16* W1h = Wfm + (sel ? 2 * 16384 : 0);
    const _Float16* W2h = Wfm + (sel ? 3 * 16384 : 16384);
    const float* B1 = sel ? Bk1 : Bq1;
    const float* B2 = sel ? Bk2 : Bq2;
    _Float16* OUT = sel ? OUTk : OUTq;

    __shared__ _Float16 xs[4 * 64 * 32];   // [kstep][row][32]
    const int t0 = blockIdx.x * 64;
    const int h = blockIdx.y;
    const int tid = threadIdx.x;
    const int w = tid >> 6;
    const int l = tid & 63;
    const int lane16 = l & 15;
    const int quad = l >> 4;
    const int skh = (((l & 3) ^ ((l >> 2) & 3)) * 8);
    const int rq8 = (quad ^ (lane16 & 3)) * 8;

#pragma unroll
    for (int c = 0; c < 4; ++c) {
        int row = c * 16 + (l >> 2);
        const _Float16* g = X + (size_t)(t0 + row) * HIDDEN + h * DKV + w * 32 + skh;
        __builtin_amdgcn_global_load_lds(
            (const __attribute__((address_space(1))) void*)g,
            (__attribute__((address_space(3))) void*)(xs + w * 2048 + c * 512), 16, 0, 0);
    }
    __syncthreads();

    floatx4 acc1[4][2], acc2[4][2];
#pragma unroll
    for (int i = 0; i < 4; ++i)
#pragma unroll
        for (int j = 0; j < 2; ++j) {
            acc1[i][j] = (floatx4){0.f, 0.f, 0.f, 0.f};
            acc2[i][j] = (floatx4){0.f, 0.f, 0.f, 0.f};
        }

#pragma unroll
    for (int s = 0; s < 4; ++s) {
        half8 a[4];
#pragma unroll
        for (int mt = 0; mt < 4; ++mt)
            a[mt] = *(const half8*)&xs[s * 2048 + (mt * 16 + lane16) * 32 + rq8];
#pragma unroll
        for (int nt = 0; nt < 2; ++nt) {
            int e = w * 32 + nt * 16 + lane16;
            half8 b1 = *(const half8*)&W1h[(size_t)e * DKV + s * 32 + quad * 8];
            half8 b2 = *(const half8*)&W2h[(size_t)e * DKV + s * 32 + quad * 8];
#pragma unroll
            for (int mt = 0; mt < 4; ++mt) {
                acc1[mt][nt] = __builtin_amdgcn_mfma_f32_16x16x32_f16(a[mt], b1, acc1[mt][nt], 0, 0, 0);
                acc2[mt][nt] = __builtin_amdgcn_mfma_f32_16x16x32_f16(a[mt], b2, acc2[mt][nt], 0, 0, 0);
            }
        }
    }

#pragma unroll
    for (int nt = 0; nt < 2; ++nt) {
        int e = w * 32 + nt * 16 + lane16;
        float b1v = B1[e], b2v = B2[e];
#pragma unroll
        for (int mt = 0; mt < 4; ++mt)
#pragma unroll
            for (int r = 0; r < 4; ++r) {
                float o = (acc1[mt][nt][r] + b1v) * (acc2[mt][nt][r] + b2v);
                OUT[(size_t)(t0 + mt * 16 + quad * 4 + r) * HIDDEN + h * DKV + e] = (_Float16)o;
            }
    }
}

// ---------------------------------------------------------------------------
// Per-chunk S^T[dv][dk] = sum_j V[j][dv] K[j][dk], MFMA.
// ---------------------------------------------------------------------------
__global__ __launch_bounds__(256) void ktv_mfma(const _Float16* __restrict__ Kf,
                                                const _Float16* __restrict__ VT,
                                                float* __restrict__ G)
{
    __shared__ _Float16 kt[128 * 72];
    const int c = blockIdx.x;
    const int bh = blockIdx.y;
    const int b = bh >> 3, h = bh & 7;
    const int tid = threadIdx.x;
    const int w = tid >> 6;
    const int l = tid & 63;
    const int lane16 = l & 15;
    const int quad = l >> 4;
    const size_t rowbase = (size_t)b * T_SEQ + (size_t)c * CHUNK_L;

    {
        const int dk0 = (tid >> 4) * 8;
        const int jb = (tid & 15) * 4;
        half8 r0 = *(const half8*)&Kf[(rowbase + jb + 0) * HIDDEN + h * DKV + dk0];
        half8 r1 = *(const half8*)&Kf[(rowbase + jb + 1) * HIDDEN + h * DKV + dk0];
        half8 r2 = *(const half8*)&Kf[(rowbase + jb + 2) * HIDDEN + h * DKV + dk0];
        half8 r3 = *(const half8*)&Kf[(rowbase + jb + 3) * HIDDEN + h * DKV + dk0];
#pragma unroll
        for (int dk = 0; dk < 8; ++dk) {
            HBits a0, a1, a2, a3;
            a0.h = r0[dk]; a1.h = r1[dk]; a2.h = r2[dk]; a3.h = r3[dk];
            unsigned int lo = ((unsigned int)a1.u << 16) | a0.u;
            unsigned int hi = ((unsigned int)a3.u << 16) | a2.u;
            *(unsigned int*)&kt[(dk0 + dk) * 72 + jb] = lo;
            *(unsigned int*)&kt[(dk0 + dk) * 72 + jb + 2] = hi;
        }
    }
    __syncthreads();

    const int m0 = (w >> 1) * 64;
    const int n0 = (w & 1) * 64;
    floatx4 acc[4][4];
#pragma unroll
    for (int i = 0; i < 4; ++i)
#pragma unroll
        for (int j = 0; j < 4; ++j)
            acc[i][j] = (floatx4){0.f, 0.f, 0.f, 0.f};

#pragma unroll
    for (int s = 0; s < 2; ++s) {
        half8 a[4], bb[4];
#pragma unroll
        for (int mt = 0; mt < 4; ++mt) {
            int dv = m0 + mt * 16 + lane16;
            a[mt] = *(const half8*)&VT[((size_t)bh * DKV + dv) * T_SEQ + c * CHUNK_L + s * 32 + quad * 8];
        }
#pragma unroll
        for (int nt = 0; nt < 4; ++nt)
            bb[nt] = *(const half8*)&kt[(n0 + nt * 16 + lane16) * 72 + s * 32 + quad * 8];
#pragma unroll
        for (int mt = 0; mt < 4; ++mt)
#pragma unroll
            for (int nt = 0; nt < 4; ++nt)
                acc[mt][nt] = __builtin_amdgcn_mfma_f32_16x16x32_f16(a[mt], bb[nt], acc[mt][nt], 0, 0, 0);
    }

    float* Gp = G + ((size_t)bh * NCH + c) * (DKV * DKV);
#pragma unroll
    for (int mt = 0; mt < 4; ++mt)
#pragma unroll
        for (int nt = 0; nt < 4; ++nt)
#pragma unroll
            for (int r = 0; r < 4; ++r)
                Gp[(size_t)(m0 + mt * 16 + quad * 4 + r) * DKV + n0 + nt * 16 + lane16] =
                    acc[mt][nt][r];
}

// ---------------------------------------------------------------------------
// Exclusive prefix over chunks; G fp32 in -> Gh fp16 out (scaled by SCALE_P).
// ---------------------------------------------------------------------------
__global__ void prefix_kernel(const float* __restrict__ G, _Float16* __restrict__ Gh)
{
    int idx = blockIdx.x * 256 + threadIdx.x;   // 16 * 16384
    int bh = idx >> 14;
    int e = idx & 16383;
    const float* p = G + (size_t)bh * NCH * 16384 + e;
    _Float16* q = Gh + (size_t)bh * NCH * 16384 + e;
    float run = 0.f;
#pragma unroll
    for (int c = 0; c < NCH; ++c) {
        q[(size_t)c * 16384] = (_Float16)(run * SCALE_P);
        run += p[(size_t)c * 16384];
    }
}

// ---------------------------------------------------------------------------
// Attention per chunk, MFMA. P-tile rows padded to 40 halfs (bank spread).
// ---------------------------------------------------------------------------
#define PSLD 40
__global__ __launch_bounds__(256) void attn_mfma(const _Float16* __restrict__ Qf,
                                                 const _Float16* __restrict__ Kf,
                                                 const _Float16* __restrict__ VT,
                                                 const _Float16* __restrict__ Gh,
                                                 _Float16* __restrict__ O)
{
    __shared__ _Float16 ps[2 * 64 * PSLD];
    const int c = blockIdx.x;
    const int bh = blockIdx.y;
    const int b = bh >> 3, h = bh & 7;
    const int tid = threadIdx.x;
    const int w = tid >> 6;
    const int l = tid & 63;
    const int lane16 = l & 15;
    const int quad = l >> 4;
    const size_t rowbase = (size_t)b * T_SEQ + (size_t)c * CHUNK_L;

    {
        const int m0 = (w >> 1) * 32;
        const int n0 = (w & 1) * 32;
        floatx4 aq[2][2];
#pragma unroll
        for (int i = 0; i < 2; ++i)
#pragma unroll
            for (int j = 0; j < 2; ++j)
                aq[i][j] = (floatx4){0.f, 0.f, 0.f, 0.f};
#pragma unroll
        for (int s = 0; s < 4; ++s) {
            half8 a[2], bb[2];
#pragma unroll
            for (int mt = 0; mt < 2; ++mt)
                a[mt] = *(const half8*)&Qf[(rowbase + m0 + mt * 16 + lane16) * HIDDEN +
                                           h * DKV + s * 32 + quad * 8];
#pragma unroll
            for (int nt = 0; nt < 2; ++nt)
                bb[nt] = *(const half8*)&Kf[(rowbase + n0 + nt * 16 + lane16) * HIDDEN +
                                            h * DKV + s * 32 + quad * 8];
#pragma unroll
            for (int mt = 0; mt < 2; ++mt)
#pragma unroll
                for (int nt = 0; nt < 2; ++nt)
                    aq[mt][nt] = __builtin_amdgcn_mfma_f32_16x16x32_f16(a[mt], bb[nt], aq[mt][nt], 0, 0, 0);
        }
#pragma unroll
        for (int mt = 0; mt < 2; ++mt)
#pragma unroll
            for (int nt = 0; nt < 2; ++nt) {
                int j = n0 + nt * 16 + lane16;
#pragma unroll
                for (int r = 0; r < 4; ++r) {
                    int i = m0 + mt * 16 + quad * 4 + r;
                    float v = (j <= i) ? aq[mt][nt][r] * SCALE_P : 0.f;
                    ps[(j >> 5) * 64 * PSLD + i * PSLD + (j & 31)] = (_Float16)v;
                }
            }
    }
    __syncthreads();

    const int n0o = w * 32;
    floatx4 accO[4][2];
#pragma unroll
    for (int i = 0; i < 4; ++i)
#pragma unroll
        for (int j = 0; j < 2; ++j)
            accO[i][j] = (floatx4){0.f, 0.f, 0.f, 0.f};

#pragma unroll
    for (int s = 0; s < 2; ++s) {
        half8 a[4], bb[2];
#pragma unroll
        for (int mt = 0; mt < 4; ++mt)
            a[mt] = *(const half8*)&ps[s * 64 * PSLD + (mt * 16 + lane16) * PSLD + quad * 8];
#pragma unroll
        for (int nt = 0; nt < 2; ++nt) {
            int dv = n0o + nt * 16 + lane16;
            bb[nt] = *(const half8*)&VT[((size_t)bh * DKV + dv) * T_SEQ + c * CHUNK_L + s * 32 + quad * 8];
        }
#pragma unroll
        for (int mt = 0; mt < 4; ++mt)
#pragma unroll
            for (int nt = 0; nt < 2; ++nt)
                accO[mt][nt] = __builtin_amdgcn_mfma_f32_16x16x32_f16(a[mt], bb[nt], accO[mt][nt], 0, 0, 0);
    }

    const _Float16* gh = Gh + ((size_t)bh * NCH + c) * (DKV * DKV);
#pragma unroll
    for (int s = 0; s < 4; ++s) {
        half8 a[4], bb[2];
#pragma unroll
        for (int mt = 0; mt < 4; ++mt)
            a[mt] = *(const half8*)&Qf[(rowbase + mt * 16 + lane16) * HIDDEN +
                                       h * DKV + s * 32 + quad * 8];
#pragma unroll
        for (int nt = 0; nt < 2; ++nt) {
            int dv = n0o + nt * 16 + lane16;
            bb[nt] = *(const half8*)&gh[(size_t)dv * DKV + s * 32 + quad * 8];
        }
#pragma unroll
        for (int mt = 0; mt < 4; ++mt)
#pragma unroll
            for (int nt = 0; nt < 2; ++nt)
                accO[mt][nt] = __builtin_amdgcn_mfma_f32_16x16x32_f16(a[mt], bb[nt], accO[mt][nt], 0, 0, 0);
    }

#pragma unroll
    for (int mt = 0; mt < 4; ++mt)
#pragma unroll
        for (int nt = 0; nt < 2; ++nt)
#pragma unroll
            for (int r = 0; r < 4; ++r)
                O[(rowbase + mt * 16 + quad * 4 + r) * HIDDEN + h * DKV + n0o + nt * 16 + lane16] =
                    (_Float16)(accO[mt][nt][r] * OEPS);
}

// ---------------------------------------------------------------------------
// Workspace map (192 MiB, phase-aliased) — unchanged from R4.
// ---------------------------------------------------------------------------
extern "C" void kernel_launch(void* const* d_in, const int* in_sizes, int n_in,
                              void* d_out, int out_size, void* d_ws, size_t ws_size,
                              hipStream_t stream)
{
    (void)in_sizes; (void)n_in; (void)out_size; (void)ws_size;
    const float* hs = (const float*)d_in[0];
    const float* wq = (const float*)d_in[1];
    const float* wk = (const float*)d_in[2];
    const float* wv = (const float*)d_in[3];
    const float* wo = (const float*)d_in[4];
    const float* cq = (const float*)d_in[5];
    const float* ck = (const float*)d_in[6];
    const float* cv = (const float*)d_in[7];
    const float* fmq_w1 = (const float*)d_in[8];
    const float* fmq_b1 = (const float*)d_in[9];
    const float* fmq_w2 = (const float*)d_in[10];
    const float* fmq_b2 = (const float*)d_in[11];
    const float* fmk_w1 = (const float*)d_in[12];
    const float* fmk_b1 = (const float*)d_in[13];
    const float* fmk_w2 = (const float*)d_in[14];
    const float* fmk_b2 = (const float*)d_in[15];
    float* out = (float*)d_out;
    char* ws = (char*)d_ws;

    const size_t MB = 1024 * 1024;
    _Float16* h16     = (_Float16*)(ws + 0);
    _Float16* wqkv16  = (_Float16*)(ws + 16 * MB);         // 3072x1024
    _Float16* wo16    = wqkv16 + (3 << 20);
    _Float16* fmw     = wqkv16 + (4 << 20);                // 4 x 16384
    _Float16* qkvlin  = (_Float16*)(ws + 32 * MB);         // [8192][3072]
    _Float16* qf16    = (_Float16*)(ws + 32 * MB);
    _Float16* kf16    = (_Float16*)(ws + 48 * MB);
    _Float16* Gh      = (_Float16*)(ws + 64 * MB);         // 32 MB
    _Float16* qc16    = (_Float16*)(ws + 80 * MB);
    _Float16* kc16    = (_Float16*)(ws + 96 * MB);
    _Float16* O16     = (_Float16*)(ws + 96 * MB);
    _Float16* vT      = (_Float16*)(ws + 112 * MB);
    float*    G       = (float*)(ws + 128 * MB);           // 64 MB

    // ---- P0: casts ----
    cast_f32_f16<<<4096, 256, 0, stream>>>(hs, h16, BT * HIDDEN / 8);
    cast4_f32_f16<<<dim3(512, 4), 256, 0, stream>>>(wq, wk, wv, wo,
                                                    wqkv16, wqkv16 + (1 << 20), wqkv16 + (2 << 20), wo16,
                                                    HIDDEN * HIDDEN / 8);
    cast4_f32_f16<<<dim3(8, 4), 256, 0, stream>>>(fmq_w1, fmq_w2, fmk_w1, fmk_w2,
                                                  fmw, fmw + 16384, fmw + 2 * 16384, fmw + 3 * 16384,
                                                  DKV * DKV / 8);

    // ---- P1: fused QKV projection (N = 3072) ----
    dim3 gqkv(3 * HIDDEN / 128, BT / 128);   // (24, 64) = 1536 blocks
    gemm_nt_f16_h16<<<gqkv, 256, 0, stream>>>(h16, wqkv16, qkvlin, BT, 3 * HIDDEN, HIDDEN);

    // ---- P2: conv + silu (q,k fused; v transposed) ----
    conv_silu_col2<<<dim3((128 * (BT / CSTRIPE)) / 256, 2), 256, 0, stream>>>(
        qkvlin, 3 * HIDDEN, cq, ck, qc16, kc16);
    dim3 cg(T_SEQ / 64, HIDDEN / 64, BATCH);
    conv_silu_T<<<cg, 256, 0, stream>>>(qkvlin + 2 * HIDDEN, 3 * HIDDEN, cv, vT);

    // ---- P3: feature maps (q,k fused) ----
    dim3 fg(BT / 64, NHEAD, 2);
    fm_mfma2<<<fg, 256, 0, stream>>>(qc16, kc16, fmw, fmq_b1, fmq_b2, fmk_b1, fmk_b2, qf16, kf16);

    // ---- P4-P6: chunked linear attention ----
    dim3 ag(NCH, BATCH * NHEAD);
    ktv_mfma<<<ag, 256, 0, stream>>>(kf16, vT, G);
    prefix_kernel<<<(16 * 16384) / 256, 256, 0, stream>>>(G, Gh);
    attn_mfma<<<ag, 256, 0, stream>>>(qf16, kf16, vT, Gh, O16);

    // ---- P7: output projection (undo SCALE_O) ----
    dim3 gg(HIDDEN / 128, BT / 128);
    gemm_nt_f16_f32<<<gg, 256, 0, stream>>>(O16, wo16, out, BT, HIDDEN, HIDDEN, 1.0f / SCALE_O);
}